// Round 11
// baseline (7544.022 us; speedup 1.0000x reference)
//
#include <hip/hip_runtime.h>
#include <hip/hip_bf16.h>

#define DI __device__ __forceinline__

typedef __attribute__((ext_vector_type(8))) short bf16x8;
typedef __attribute__((ext_vector_type(4))) float f32x4;

DI float fmulr(float a, float b){ return __fmul_rn(a,b); }
DI float faddr(float a, float b){ return __fadd_rn(a,b); }
DI float fsubr(float a, float b){ return __fsub_rn(a,b); }
DI float dist2e(float x,float y,float z,float cx,float cy,float cz){
  float dx=fsubr(x,cx), dy=fsubr(y,cy), dz=fsubr(z,cz);
  return faddr(faddr(fmulr(dx,dx),fmulr(dy,dy)),fmulr(dz,dz));
}
DI unsigned short f2bf(float f){ __hip_bfloat16 h=__float2bfloat16(f); return *reinterpret_cast<unsigned short*>(&h); }

// DPP-based wave64 max: row_shr 1/2/4/8 then row_bcast:15, row_bcast:31 -> lane63 holds max.
template<int C> DI float dmax_step(float x){
  int y=__builtin_amdgcn_update_dpp(0, __float_as_int(x), C, 0xF, 0xF, true);
  return fmaxf(x, __int_as_float(y));
}

// ---------------- FPS: 8 blocks (one per batch), 256 threads (4 waves), 16 pts/lane -------
// Local argmax via a 15-node PAYLOAD select tree (val,x,y,z,idx) with ALL-STATIC
// indices (rule #20: runtime-indexed register arrays go to scratch -- r10 lesson).
// Left-preference (>=) at each node == first-occurrence tie-break. Winner lane
// publishes u64 key + float4 coords; post-barrier readback is parallel slot reads
// + cndmask tree (no dependent sp4[cur] read on the critical path).
// key = (dist<<32) | (0xFFFFFFFF - idx): max == max dist, tie -> lowest idx.
__global__ __launch_bounds__(256) void fps_kernel(const float* __restrict__ xyz, float* __restrict__ out0){
  extern __shared__ char smem[];
  float4* sp4=(float4*)smem;
  float* spf=(float*)smem;
  unsigned long long* keys=(unsigned long long*)(smem+65536);   // [2][4]
  float4* wco=(float4*)(smem+65536+64);                          // [2][4]
  int b=blockIdx.x, tid=threadIdx.x;
  const float* xb = xyz + (size_t)b*12288;
  for(int e=tid;e<12288;e+=256){ int p=e/3, c=e-3*p; spf[4*p+c]=xb[e]; }
  __syncthreads();
  float px[16],py[16],pz[16],dist[16];
  int p0 = tid*16;
  #pragma unroll
  for(int j=0;j<16;j++){ float4 r=sp4[p0+j]; px[j]=r.x; py[j]=r.y; pz[j]=r.z; dist[j]=1e10f; }
  int cur=0;
  float4 cc0=sp4[0];
  float cx=cc0.x, cy=cc0.y, cz=cc0.z;
  int w=tid>>6, lane=tid&63;
  int c0s=0,c1s=0,c2s=0,c3s=0;
  float* ob = out0 + (size_t)b*1024*3;
  #pragma unroll 1
  for(int t=0;t<1024;t++){
    bool mine = ((t&255)==tid);
    int hi = t>>8;
    c0s = (mine && hi==0) ? cur : c0s;
    c1s = (mine && hi==1) ? cur : c1s;
    c2s = (mine && hi==2) ? cur : c2s;
    c3s = (mine && hi==3) ? cur : c3s;
    float nd[16];
    #pragma unroll
    for(int j=0;j<16;j++){
      float d=dist2e(px[j],py[j],pz[j],cx,cy,cz);
      float m=fminf(dist[j],d); dist[j]=m; nd[j]=m;
    }
    // payload tree: (val, x, y, z, idx), static indices only
    float v1[8],x1[8],y1[8],z1[8]; int i1[8];
    #pragma unroll
    for(int k=0;k<8;k++){
      bool c=nd[2*k]>=nd[2*k+1];
      v1[k]=c?nd[2*k]:nd[2*k+1];
      x1[k]=c?px[2*k]:px[2*k+1];
      y1[k]=c?py[2*k]:py[2*k+1];
      z1[k]=c?pz[2*k]:pz[2*k+1];
      i1[k]=c?(p0+2*k):(p0+2*k+1);
    }
    float v2[4],x2[4],y2[4],z2[4]; int i2[4];
    #pragma unroll
    for(int k=0;k<4;k++){
      bool c=v1[2*k]>=v1[2*k+1];
      v2[k]=c?v1[2*k]:v1[2*k+1];
      x2[k]=c?x1[2*k]:x1[2*k+1];
      y2[k]=c?y1[2*k]:y1[2*k+1];
      z2[k]=c?z1[2*k]:z1[2*k+1];
      i2[k]=c?i1[2*k]:i1[2*k+1];
    }
    float v3[2],x3[2],y3[2],z3[2]; int i3[2];
    #pragma unroll
    for(int k=0;k<2;k++){
      bool c=v2[2*k]>=v2[2*k+1];
      v3[k]=c?v2[2*k]:v2[2*k+1];
      x3[k]=c?x2[2*k]:x2[2*k+1];
      y3[k]=c?y2[2*k]:y2[2*k+1];
      z3[k]=c?z2[2*k]:z2[2*k+1];
      i3[k]=c?i2[2*k]:i2[2*k+1];
    }
    bool cf=v3[0]>=v3[1];
    float bv=cf?v3[0]:v3[1];
    float tx=cf?x3[0]:x3[1], ty=cf?y3[0]:y3[1], tz=cf?z3[0]:z3[1];
    int   bi=cf?i3[0]:i3[1];
    // DPP value-only wave max
    float x=bv;
    x=dmax_step<0x111>(x); x=dmax_step<0x112>(x); x=dmax_step<0x114>(x); x=dmax_step<0x118>(x);
    x=dmax_step<0x142>(x); x=dmax_step<0x143>(x);
    float wv=__int_as_float(__builtin_amdgcn_readlane(__float_as_int(x),63));
    unsigned long long em=__ballot(bv==wv);
    int L=(int)(__ffsll(em)-1);
    int par=t&1;
    if(lane==L){
      keys[par*4+w] = ((unsigned long long)__float_as_uint(wv)<<32)
                    | (unsigned long long)(0xFFFFFFFFu-(unsigned)bi);
      wco[par*4+w]  = make_float4(tx,ty,tz,0.f);
    }
    __syncthreads();
    ulonglong2 ka=*(const ulonglong2*)(keys+par*4);
    ulonglong2 kb=*(const ulonglong2*)(keys+par*4+2);
    float4 q0=wco[par*4+0], q1=wco[par*4+1], q2=wco[par*4+2], q3=wco[par*4+3];
    bool s01 = ka.x>=ka.y; unsigned long long k01 = s01?ka.x:ka.y;
    bool s23 = kb.x>=kb.y; unsigned long long k23 = s23?kb.x:kb.y;
    float c01x=s01?q0.x:q1.x, c01y=s01?q0.y:q1.y, c01z=s01?q0.z:q1.z;
    float c23x=s23?q2.x:q3.x, c23y=s23?q2.y:q3.y, c23z=s23?q2.z:q3.z;
    bool sf = k01>=k23;
    unsigned long long k = sf?k01:k23;
    cx = sf?c01x:c23x; cy = sf?c01y:c23y; cz = sf?c01z:c23z;
    cur=(int)(0xFFFFFFFFu-(unsigned)(k&0xFFFFFFFFull));
  }
  { int t0=tid;     float4 c=sp4[c0s]; ob[t0*3]=c.x; ob[t0*3+1]=c.y; ob[t0*3+2]=c.z; }
  { int t1=tid+256; float4 c=sp4[c1s]; ob[t1*3]=c.x; ob[t1*3+1]=c.y; ob[t1*3+2]=c.z; }
  { int t2=tid+512; float4 c=sp4[c2s]; ob[t2*3]=c.x; ob[t2*3+1]=c.y; ob[t2*3+2]=c.z; }
  { int t3=tid+768; float4 c=sp4[c3s]; ob[t3*3]=c.x; ob[t3*3+1]=c.y; ob[t3*3+2]=c.z; }
}

// ---------------- ball query: 4 waves/block share one batch staged in LDS ----------------
__global__ __launch_bounds__(256) void ballq_kernel(const float* __restrict__ xyz, const float* __restrict__ out0,
        int* __restrict__ idxw, float* __restrict__ out2){
  __shared__ float sp[12288];
  int tid=threadIdx.x;
  int g = blockIdx.x*4 + (tid>>6);
  int lane = tid&63;
  int b = blockIdx.x>>8;
  const float* xb = xyz + (size_t)b*4096*3;
  const float4* src=(const float4*)xb; float4* dst=(float4*)sp;
  #pragma unroll
  for(int i=0;i<12;i++) dst[i*256+tid]=src[i*256+tid];
  __syncthreads();
  float cx=out0[(size_t)g*3], cy=out0[(size_t)g*3+1], cz=out0[(size_t)g*3+2];
  const float R2 = (float)(0.2*0.2);
  int cnt=0, firstp=0; bool haveFirst=false;
  for(int c=0;c<64;c++){
    int p=c*64+lane;
    float x=sp[3*p], y=sp[3*p+1], z=sp[3*p+2];
    float d2=dist2e(x,y,z,cx,cy,cz);
    bool inb = d2 < R2;
    unsigned long long mask=__ballot(inb);
    if(!haveFirst && mask){ firstp = c*64 + (__ffsll((unsigned long long)mask)-1); haveFirst=true; }
    int pos = cnt + (int)__popcll(mask & ((1ull<<lane)-1ull));
    if(inb && pos<32){ idxw[(size_t)g*32+pos]=p; out2[(size_t)g*32+pos]=(float)p; }
    cnt += (int)__popcll(mask);
    if(cnt>=32) break;
  }
  if(cnt<32){
    for(int j=cnt+lane; j<32; j+=64){ idxw[(size_t)g*32+j]=firstp; out2[(size_t)g*32+j]=(float)firstp; }
  }
}

// ---------------- layer0 via MFMA: gather->bf16, K=64 MFMA + scalar xyz part ----------
__global__ __launch_bounds__(256) void l0_mfma(const float* __restrict__ xyz, const float* __restrict__ pts,
    const float* __restrict__ out0, const int* __restrict__ idxw,
    const float* __restrict__ W0, const float* __restrict__ b0,
    __hip_bfloat16* __restrict__ y0, float* __restrict__ P){
  __shared__ unsigned short xg[64*72];
  __shared__ unsigned short wt[64*72];
  __shared__ unsigned short yt[64*72];
  __shared__ float xyzl[64][4];
  __shared__ float w0c[3][64];
  __shared__ float ps[4][64];
  __shared__ float qs[4][64];
  int tid=threadIdx.x; int base=blockIdx.x*64;
  int w=tid>>6, lane=tid&63;
  for(int i=0;i<16;i++){
    int r=w*16+i; int R=base+r;
    int g=R>>5; int b=g>>10; int p=idxw[R];
    xg[r*72+lane] = f2bf(pts[((size_t)b*4096+(size_t)p)*64+lane]);
    if(lane<3) xyzl[r][lane] = fsubr(xyz[((size_t)b*4096+(size_t)p)*3+lane], out0[(size_t)g*3+lane]);
  }
  for(int e=tid; e<4096; e+=256){
    int k=e>>6, n=e&63;
    wt[n*72+k]=f2bf(W0[(3+k)*64+n]);
  }
  if(tid<192){ int r=tid>>6, n=tid&63; w0c[r][n]=W0[r*64+n]; }
  __syncthreads();
  int m=lane&15, kg=lane>>4;
  f32x4 acc[4];
  #pragma unroll
  for(int t=0;t<4;t++){
    int col=t*16+m;
    float bb=b0[col], wx=w0c[0][col], wy=w0c[1][col], wz=w0c[2][col];
    #pragma unroll
    for(int rg=0;rg<4;rg++){
      int row=w*16+kg*4+rg;
      acc[t][rg]=bb + xyzl[row][0]*wx + xyzl[row][1]*wy + xyzl[row][2]*wz;
    }
  }
  #pragma unroll
  for(int ks=0; ks<2; ks++){
    int k0=ks*32+kg*8;
    bf16x8 af = *(bf16x8*)&xg[(w*16+m)*72 + k0];
    #pragma unroll
    for(int t=0;t<4;t++){
      bf16x8 bfr = *(bf16x8*)&wt[(t*16+m)*72 + k0];
      acc[t]=__builtin_amdgcn_mfma_f32_16x16x32_bf16(af,bfr,acc[t],0,0,0);
    }
  }
  #pragma unroll
  for(int t=0;t<4;t++){
    float s=0.f,q=0.f;
    #pragma unroll
    for(int rg=0;rg<4;rg++){
      float v=acc[t][rg];
      s+=v; q+=v*v;
      yt[(w*16+kg*4+rg)*72 + t*16+m]=f2bf(v);
    }
    s+=__shfl_xor(s,16); q+=__shfl_xor(q,16);
    s+=__shfl_xor(s,32); q+=__shfl_xor(q,32);
    if(kg==0){ ps[w][t*16+m]=s; qs[w][t*16+m]=q; }
  }
  __syncthreads();
  if(tid<64){
    float s=ps[0][tid]+ps[1][tid]+ps[2][tid]+ps[3][tid];
    float q=qs[0][tid]+qs[1][tid]+qs[2][tid]+qs[3][tid];
    P[(size_t)tid*4096+blockIdx.x]=s;
    P[(size_t)(128+tid)*4096+blockIdx.x]=q;
  }
  for(int e=tid; e<512; e+=256){
    int r=e>>3, c0=(e&7)*8;
    *reinterpret_cast<uint4*>(y0 + ((size_t)base+r)*64 + c0) = *reinterpret_cast<uint4*>(&yt[r*72+c0]);
  }
}

// ---------------- mid layers via MFMA, ss preloaded to LDS ----------
template<int CIN,int COUT>
__global__ __launch_bounds__(256) void lmid_mfma(const __hip_bfloat16* __restrict__ xin,
    const float* __restrict__ ssIn, const float* __restrict__ W, const float* __restrict__ bias,
    __hip_bfloat16* __restrict__ yout, float* __restrict__ P){
  constexpr int XS = CIN+8;
  constexpr int YS = COUT+8;
  constexpr int NT = COUT/16;
  __shared__ unsigned short xt[64*XS];
  __shared__ unsigned short wt[COUT*XS];
  __shared__ unsigned short yt[64*YS];
  __shared__ float ps[4][COUT];
  __shared__ float qs[4][COUT];
  __shared__ float ssl[256];
  int tid=threadIdx.x; size_t base=(size_t)blockIdx.x*64;
  int w=tid>>6, lane=tid&63;
  ssl[tid]=ssIn[tid];
  __syncthreads();
  for(int e=tid; e<64*CIN/8; e+=256){
    int r=e/(CIN/8), c0=(e%(CIN/8))*8;
    uint4 raw = *reinterpret_cast<const uint4*>(xin + (base+(size_t)r)*CIN + c0);
    unsigned u[4]={raw.x,raw.y,raw.z,raw.w};
    unsigned short* dst=&xt[r*XS+c0];
    #pragma unroll
    for(int k2=0;k2<4;k2++){
      int c=c0+2*k2;
      float lo=__uint_as_float(u[k2]<<16);
      float hi=__uint_as_float(u[k2]&0xFFFF0000u);
      float a=lo*ssl[c]+ssl[128+c]; a=a>0.f?a:0.f;
      float bq=hi*ssl[c+1]+ssl[128+c+1]; bq=bq>0.f?bq:0.f;
      dst[2*k2]=f2bf(a); dst[2*k2+1]=f2bf(bq);
    }
  }
  for(int e=tid; e<CIN*COUT; e+=256){
    int k=e/COUT, n=e-k*COUT;
    wt[n*XS+k]=f2bf(W[e]);
  }
  __syncthreads();
  f32x4 acc[NT];
  #pragma unroll
  for(int t=0;t<NT;t++) acc[t]=(f32x4){0.f,0.f,0.f,0.f};
  int m=lane&15, kg=lane>>4;
  #pragma unroll
  for(int ks=0; ks<CIN/32; ks++){
    int k0=ks*32+kg*8;
    bf16x8 af = *(bf16x8*)&xt[(w*16+m)*XS + k0];
    #pragma unroll
    for(int t=0;t<NT;t++){
      bf16x8 bfr = *(bf16x8*)&wt[(t*16+m)*XS + k0];
      acc[t]=__builtin_amdgcn_mfma_f32_16x16x32_bf16(af,bfr,acc[t],0,0,0);
    }
  }
  #pragma unroll
  for(int t=0;t<NT;t++){
    float bv=bias[t*16+m];
    float s=0.f,q=0.f;
    #pragma unroll
    for(int rg=0;rg<4;rg++){
      float v=acc[t][rg]+bv;
      s+=v; q+=v*v;
      yt[(w*16+kg*4+rg)*YS + t*16+m]=f2bf(v);
    }
    s+=__shfl_xor(s,16); q+=__shfl_xor(q,16);
    s+=__shfl_xor(s,32); q+=__shfl_xor(q,32);
    if(kg==0){ ps[w][t*16+m]=s; qs[w][t*16+m]=q; }
  }
  __syncthreads();
  if(tid<COUT){
    float s=ps[0][tid]+ps[1][tid]+ps[2][tid]+ps[3][tid];
    float q=qs[0][tid]+qs[1][tid]+qs[2][tid]+qs[3][tid];
    P[(size_t)tid*4096+blockIdx.x]=s;
    P[(size_t)(128+tid)*4096+blockIdx.x]=q;
  }
  for(int e=tid; e<64*COUT/8; e+=256){
    int r=e/(COUT/8), c0=(e%(COUT/8))*8;
    *reinterpret_cast<uint4*>(yout + (base+(size_t)r)*COUT + c0) = *reinterpret_cast<uint4*>(&yt[r*YS+c0]);
  }
}

// ---------------- finalize stats: scale/shift per channel ----------------
__global__ void fin_kernel(const float* __restrict__ P, const float* __restrict__ gg, const float* __restrict__ be,
                           float* __restrict__ ss){
  int ch=blockIdx.x; int lane=threadIdx.x;
  float s=0.f,q=0.f;
  for(int blk=lane; blk<4096; blk+=64){ s+=P[(size_t)ch*4096+blk]; q+=P[(size_t)(128+ch)*4096+blk]; }
  #pragma unroll
  for(int m=32;m>=1;m>>=1){ s+=__shfl_xor(s,m); q+=__shfl_xor(q,m); }
  if(lane==0){
    const float invNT = 1.0f/262144.0f;
    float mean=s*invNT; float var=q*invNT - mean*mean;
    float scale=gg[ch]/sqrtf(var+1e-3f);
    ss[ch]=scale; ss[128+ch]=be[ch]-mean*scale;
  }
}

// ---------------- finalize stats (layer2) + M = Wq*Wk^T fused ----------------
__global__ void fin2_kernel(const float* __restrict__ P, const float* __restrict__ gg, const float* __restrict__ be,
                            float* __restrict__ ss, const float* __restrict__ Wq, const float* __restrict__ Wk,
                            float* __restrict__ M){
  int ch=blockIdx.x; int lane=threadIdx.x;
  float s=0.f,q=0.f;
  for(int blk=lane; blk<4096; blk+=64){ s+=P[(size_t)ch*4096+blk]; q+=P[(size_t)(128+ch)*4096+blk]; }
  float m0=0.f,m1=0.f,m2=0.f;
  #pragma unroll
  for(int dd=0; dd<2; dd++){
    int d=lane+dd*64;
    float wk=Wk[ch*128+d];
    m0+=Wq[d]*wk; m1+=Wq[128+d]*wk; m2+=Wq[256+d]*wk;
  }
  #pragma unroll
  for(int m=32;m>=1;m>>=1){
    s+=__shfl_xor(s,m); q+=__shfl_xor(q,m);
    m0+=__shfl_xor(m0,m); m1+=__shfl_xor(m1,m); m2+=__shfl_xor(m2,m);
  }
  if(lane==0){
    const float invNT = 1.0f/262144.0f;
    float mean=s*invNT; float var=q*invNT - mean*mean;
    float scale=gg[ch]/sqrtf(var+1e-3f);
    ss[ch]=scale; ss[128+ch]=be[ch]-mean*scale;
    M[ch]=m0; M[128+ch]=m1; M[256+ch]=m2;
  }
}

// ---------------- per-group: bn2+relu, u=center@M, scores, softmax, hbar, out1=hbar@Wv ----
__global__ __launch_bounds__(256) void sh_kernel(const __hip_bfloat16* __restrict__ y2,
    const float* __restrict__ ss2, const float* __restrict__ M, const float* __restrict__ out0,
    const float* __restrict__ Wv, float* __restrict__ out1){
  __shared__ float h[2][32*130];
  __shared__ float uLds[2][128];
  __shared__ float sLds[2][32];
  __shared__ float partLds[2][4][32];
  __shared__ float ssl[256];
  __shared__ float hbL[2][128];
  int tid=threadIdx.x; int grp=tid>>7, t=tid&127;
  size_t g=(size_t)blockIdx.x*2+grp;
  ssl[tid]=ss2[tid];
  __syncthreads();
  #pragma unroll
  for(int i=0;i<4;i++){
    int e=i*128+t;
    int row=e>>4, c0=(e&15)*8;
    uint4 raw=*reinterpret_cast<const uint4*>(y2+(g*32+(size_t)row)*128+c0);
    unsigned u[4]={raw.x,raw.y,raw.z,raw.w};
    #pragma unroll
    for(int k=0;k<4;k++){
      int c=c0+2*k;
      float lo=__uint_as_float(u[k]<<16), hi=__uint_as_float(u[k]&0xFFFF0000u);
      float a=lo*ssl[c]+ssl[128+c]; float bq=hi*ssl[c+1]+ssl[128+c+1];
      h[grp][row*130+c]  = a>0.f?a:0.f;
      h[grp][row*130+c+1]= bq>0.f?bq:0.f;
    }
  }
  float cx=out0[g*3], cy=out0[g*3+1], cz=out0[g*3+2];
  uLds[grp][t]=cx*M[t]+cy*M[128+t]+cz*M[256+t];
  __syncthreads();
  {
    int row=t&31, q=t>>5;
    float sc=0.f;
    const float* hr=&h[grp][row*130];
    const float* ur=&uLds[grp][0];
    #pragma unroll
    for(int c=0;c<32;c++) sc += hr[q*32+c]*ur[q*32+c];
    partLds[grp][q][row]=sc;
  }
  __syncthreads();
  if(t<32){
    float s=(partLds[grp][0][t]+partLds[grp][1][t])+(partLds[grp][2][t]+partLds[grp][3][t]);
    s*=0.08838834764831845f; // 1/sqrt(128)
    float mx=s;
    #pragma unroll
    for(int m=16;m>=1;m>>=1) mx=fmaxf(mx,__shfl_xor(mx,m));
    float p=expf(s-mx);
    float sum=p;
    #pragma unroll
    for(int m=16;m>=1;m>>=1) sum+=__shfl_xor(sum,m);
    sLds[grp][t]=p/sum;
  }
  __syncthreads();
  float hb=0.f;
  for(int k=0;k<32;k++) hb+=sLds[grp][k]*h[grp][k*130+t];
  hbL[grp][t]=hb;
  __syncthreads();
  // out1 = hbar @ Wv (Wv rows broadcast via L1/L2; coalesced per 128-thread group)
  float acc=0.f;
  #pragma unroll 4
  for(int c=0;c<128;c++) acc += hbL[grp][c]*Wv[c*128+t];
  out1[g*128+t]=acc;
}

extern "C" void kernel_launch(void* const* d_in, const int* in_sizes, int n_in,
                              void* d_out, int out_size, void* d_ws, size_t ws_size,
                              hipStream_t stream){
  (void)in_sizes; (void)n_in; (void)out_size; (void)ws_size;
  const float* xyz=(const float*)d_in[0];
  const float* pts=(const float*)d_in[1];
  const float* W0=(const float*)d_in[2];  const float* b0=(const float*)d_in[3];
  const float* g0=(const float*)d_in[4];  const float* be0=(const float*)d_in[5];
  const float* W1=(const float*)d_in[6];  const float* b1=(const float*)d_in[7];
  const float* g1=(const float*)d_in[8];  const float* be1=(const float*)d_in[9];
  const float* W2=(const float*)d_in[10]; const float* b2=(const float*)d_in[11];
  const float* g2=(const float*)d_in[12]; const float* be2=(const float*)d_in[13];
  const float* Wq=(const float*)d_in[14]; const float* Wk=(const float*)d_in[15];
  const float* Wv=(const float*)d_in[16];
  float* out0=(float*)d_out;
  float* out1=out0 + (size_t)8*1024*3;
  float* out2=out1 + (size_t)8192*128;

  char* ws=(char*)d_ws; size_t off=0;
  int* idxw=(int*)(ws+off);                    off += (size_t)8192*32*4;
  __hip_bfloat16* fa=(__hip_bfloat16*)(ws+off); off += (size_t)262144*64*2;
  __hip_bfloat16* fb=(__hip_bfloat16*)(ws+off); off += (size_t)262144*64*2;
  __hip_bfloat16* fc=(__hip_bfloat16*)(ws+off); off += (size_t)262144*128*2;
  float* P =(float*)(ws+off);                  off += (size_t)256*4096*4;
  float* ss0=(float*)(ws+off);                 off += 256*4;
  float* ss1=(float*)(ws+off);                 off += 256*4;
  float* ss2=(float*)(ws+off);                 off += 256*4;
  float* M =(float*)(ws+off);                  off += 3*128*4 + 128;

  hipLaunchKernelGGL(fps_kernel,   dim3(8),    dim3(256), 65536+64+128, stream, xyz, out0);
  hipLaunchKernelGGL(ballq_kernel, dim3(2048), dim3(256),  0, stream, xyz, out0, idxw, out2);
  hipLaunchKernelGGL(l0_mfma,      dim3(4096), dim3(256),  0, stream, xyz, pts, out0, idxw, W0, b0, fa, P);
  hipLaunchKernelGGL(fin_kernel,   dim3(64),   dim3(64),   0, stream, P, g0, be0, ss0);
  hipLaunchKernelGGL((lmid_mfma<64,64>),  dim3(4096), dim3(256), 0, stream, fa, ss0, W1, b1, fb, P);
  hipLaunchKernelGGL(fin_kernel,   dim3(64),   dim3(64),   0, stream, P, g1, be1, ss1);
  hipLaunchKernelGGL((lmid_mfma<64,128>), dim3(4096), dim3(256), 0, stream, fb, ss1, W2, b2, fc, P);
  hipLaunchKernelGGL(fin2_kernel,  dim3(128),  dim3(64),   0, stream, P, g2, be2, ss2, Wq, Wk, M);
  hipLaunchKernelGGL(sh_kernel,    dim3(4096), dim3(256),  0, stream, fc, ss2, M, out0, Wv, out1);
}

// Round 12
// 884.194 us; speedup vs baseline: 8.5321x; 8.5321x over previous
//
#include <hip/hip_runtime.h>
#include <hip/hip_bf16.h>

#define DI __device__ __forceinline__

typedef __attribute__((ext_vector_type(8))) short bf16x8;
typedef __attribute__((ext_vector_type(4))) float f32x4;

DI float fmulr(float a, float b){ return __fmul_rn(a,b); }
DI float faddr(float a, float b){ return __fadd_rn(a,b); }
DI float fsubr(float a, float b){ return __fsub_rn(a,b); }
DI float dist2e(float x,float y,float z,float cx,float cy,float cz){
  float dx=fsubr(x,cx), dy=fsubr(y,cy), dz=fsubr(z,cz);
  return faddr(faddr(fmulr(dx,dx),fmulr(dy,dy)),fmulr(dz,dz));
}
DI unsigned short f2bf(float f){ __hip_bfloat16 h=__float2bfloat16(f); return *reinterpret_cast<unsigned short*>(&h); }

// DPP-based wave64 max: row_shr 1/2/4/8 then row_bcast:15, row_bcast:31 -> lane63 holds max.
template<int C> DI float dmax_step(float x){
  int y=__builtin_amdgcn_update_dpp(0, __float_as_int(x), C, 0xF, 0xF, true);
  return fmaxf(x, __int_as_float(y));
}

// ---------------- FPS (r5 version, measured 622us — FROZEN) ----------------
// 8 blocks, 256 threads, 16 pts/lane. Minimal live register state (px/py/pz/dist/nd
// only) — payload-carrying variants (r10/r11) spill to scratch and regress 2-12x.
__global__ __launch_bounds__(256) void fps_kernel(const float* __restrict__ xyz, float* __restrict__ out0){
  __shared__ float4 sp4[4096];
  float* spf=(float*)sp4;
  int* spi=(int*)sp4;
  int b=blockIdx.x, tid=threadIdx.x;
  const float* xb = xyz + (size_t)b*4096*3;
  for(int e=tid;e<12288;e+=256){
    int p=e/3, c=e-3*p;
    spf[4*p+c]=xb[e];
  }
  __syncthreads();
  float px[16],py[16],pz[16],dist[16];
  int p0 = tid*16;
  #pragma unroll
  for(int j=0;j<16;j++){ float4 r=sp4[p0+j]; px[j]=r.x; py[j]=r.y; pz[j]=r.z; dist[j]=1e10f; }
  int cur=0;
  float4 cc0=sp4[0];
  float cx=cc0.x, cy=cc0.y, cz=cc0.z;
  int w=tid>>6, lane=tid&63;
  int c0s=0,c1s=0,c2s=0,c3s=0;
  float* ob = out0 + (size_t)b*1024*3;
  #pragma unroll 1
  for(int t=0;t<1024;t++){
    bool mine = ((t&255)==tid);
    int hi = t>>8;
    c0s = (mine && hi==0) ? cur : c0s;
    c1s = (mine && hi==1) ? cur : c1s;
    c2s = (mine && hi==2) ? cur : c2s;
    c3s = (mine && hi==3) ? cur : c3s;
    float nd[16];
    #pragma unroll
    for(int j=0;j<16;j++){
      float d=dist2e(px[j],py[j],pz[j],cx,cy,cz);
      float m=fminf(dist[j],d); dist[j]=m; nd[j]=m;
    }
    float a0=fmaxf(nd[0],nd[1]), a1=fmaxf(nd[2],nd[3]), a2=fmaxf(nd[4],nd[5]), a3=fmaxf(nd[6],nd[7]);
    float a4=fmaxf(nd[8],nd[9]), a5=fmaxf(nd[10],nd[11]), a6=fmaxf(nd[12],nd[13]), a7=fmaxf(nd[14],nd[15]);
    float b0=fmaxf(a0,a1), b1=fmaxf(a2,a3), b2=fmaxf(a4,a5), b3=fmaxf(a6,a7);
    float bv=fmaxf(fmaxf(b0,b1),fmaxf(b2,b3));
    unsigned msk=0u;
    #pragma unroll
    for(int j=0;j<16;j++) msk |= (nd[j]==bv) ? (1u<<j) : 0u;
    int bj=__ffs(msk)-1;
    int bi=p0+bj;
    float x=bv;
    x=dmax_step<0x111>(x); x=dmax_step<0x112>(x); x=dmax_step<0x114>(x); x=dmax_step<0x118>(x);
    x=dmax_step<0x142>(x); x=dmax_step<0x143>(x);
    float wv=__int_as_float(__builtin_amdgcn_readlane(__float_as_int(x),63));
    unsigned long long em=__ballot(bv==wv);
    int L=(int)(__ffsll(em)-1);
    int wbi=__builtin_amdgcn_readlane(bi,L);
    int par=t&1;
    if(lane==0){
      spf[4*(par*8+w)+3]=wv;
      spi[4*(par*8+4+w)+3]=wbi;
    }
    __syncthreads();
    float w0=spf[4*(par*8+0)+3], w1=spf[4*(par*8+1)+3], w2=spf[4*(par*8+2)+3], w3=spf[4*(par*8+3)+3];
    int   i0=spi[4*(par*8+4)+3], i1=spi[4*(par*8+5)+3], i2=spi[4*(par*8+6)+3], i3=spi[4*(par*8+7)+3];
    float mv=fmaxf(fmaxf(w0,w1),fmaxf(w2,w3));
    int u0=(w0==mv)?i0:0x7fffffff, u1=(w1==mv)?i1:0x7fffffff;
    int u2=(w2==mv)?i2:0x7fffffff, u3=(w3==mv)?i3:0x7fffffff;
    cur=min(min(u0,u1),min(u2,u3));
    float4 cc=sp4[cur]; cx=cc.x; cy=cc.y; cz=cc.z;
  }
  { int t0=tid;     float4 c=sp4[c0s]; ob[t0*3]=c.x; ob[t0*3+1]=c.y; ob[t0*3+2]=c.z; }
  { int t1=tid+256; float4 c=sp4[c1s]; ob[t1*3]=c.x; ob[t1*3+1]=c.y; ob[t1*3+2]=c.z; }
  { int t2=tid+512; float4 c=sp4[c2s]; ob[t2*3]=c.x; ob[t2*3+1]=c.y; ob[t2*3+2]=c.z; }
  { int t3=tid+768; float4 c=sp4[c3s]; ob[t3*3]=c.x; ob[t3*3+1]=c.y; ob[t3*3+2]=c.z; }
}

// ---------------- ball query: 4 waves/block share one batch staged in LDS ----------------
__global__ __launch_bounds__(256) void ballq_kernel(const float* __restrict__ xyz, const float* __restrict__ out0,
        int* __restrict__ idxw, float* __restrict__ out2){
  __shared__ float sp[12288];
  int tid=threadIdx.x;
  int g = blockIdx.x*4 + (tid>>6);
  int lane = tid&63;
  int b = blockIdx.x>>8;
  const float* xb = xyz + (size_t)b*4096*3;
  const float4* src=(const float4*)xb; float4* dst=(float4*)sp;
  #pragma unroll
  for(int i=0;i<12;i++) dst[i*256+tid]=src[i*256+tid];
  __syncthreads();
  float cx=out0[(size_t)g*3], cy=out0[(size_t)g*3+1], cz=out0[(size_t)g*3+2];
  const float R2 = (float)(0.2*0.2);
  int cnt=0, firstp=0; bool haveFirst=false;
  for(int c=0;c<64;c++){
    int p=c*64+lane;
    float x=sp[3*p], y=sp[3*p+1], z=sp[3*p+2];
    float d2=dist2e(x,y,z,cx,cy,cz);
    bool inb = d2 < R2;
    unsigned long long mask=__ballot(inb);
    if(!haveFirst && mask){ firstp = c*64 + (__ffsll((unsigned long long)mask)-1); haveFirst=true; }
    int pos = cnt + (int)__popcll(mask & ((1ull<<lane)-1ull));
    if(inb && pos<32){ idxw[(size_t)g*32+pos]=p; out2[(size_t)g*32+pos]=(float)p; }
    cnt += (int)__popcll(mask);
    if(cnt>=32) break;
  }
  if(cnt<32){
    for(int j=cnt+lane; j<32; j+=64){ idxw[(size_t)g*32+j]=firstp; out2[(size_t)g*32+j]=(float)firstp; }
  }
}

// ---------------- layer0 via MFMA: gather->bf16, K=64 MFMA + scalar xyz part ----------
__global__ __launch_bounds__(256) void l0_mfma(const float* __restrict__ xyz, const float* __restrict__ pts,
    const float* __restrict__ out0, const int* __restrict__ idxw,
    const float* __restrict__ W0, const float* __restrict__ b0,
    __hip_bfloat16* __restrict__ y0, float* __restrict__ P){
  __shared__ unsigned short xg[64*72];
  __shared__ unsigned short wt[64*72];
  __shared__ unsigned short yt[64*72];
  __shared__ float xyzl[64][4];
  __shared__ float w0c[3][64];
  __shared__ float ps[4][64];
  __shared__ float qs[4][64];
  int tid=threadIdx.x; int base=blockIdx.x*64;
  int w=tid>>6, lane=tid&63;
  for(int i=0;i<16;i++){
    int r=w*16+i; int R=base+r;
    int g=R>>5; int b=g>>10; int p=idxw[R];
    xg[r*72+lane] = f2bf(pts[((size_t)b*4096+(size_t)p)*64+lane]);
    if(lane<3) xyzl[r][lane] = fsubr(xyz[((size_t)b*4096+(size_t)p)*3+lane], out0[(size_t)g*3+lane]);
  }
  for(int e=tid; e<4096; e+=256){
    int k=e>>6, n=e&63;
    wt[n*72+k]=f2bf(W0[(3+k)*64+n]);
  }
  if(tid<192){ int r=tid>>6, n=tid&63; w0c[r][n]=W0[r*64+n]; }
  __syncthreads();
  int m=lane&15, kg=lane>>4;
  f32x4 acc[4];
  #pragma unroll
  for(int t=0;t<4;t++){
    int col=t*16+m;
    float bb=b0[col], wx=w0c[0][col], wy=w0c[1][col], wz=w0c[2][col];
    #pragma unroll
    for(int rg=0;rg<4;rg++){
      int row=w*16+kg*4+rg;
      acc[t][rg]=bb + xyzl[row][0]*wx + xyzl[row][1]*wy + xyzl[row][2]*wz;
    }
  }
  #pragma unroll
  for(int ks=0; ks<2; ks++){
    int k0=ks*32+kg*8;
    bf16x8 af = *(bf16x8*)&xg[(w*16+m)*72 + k0];
    #pragma unroll
    for(int t=0;t<4;t++){
      bf16x8 bfr = *(bf16x8*)&wt[(t*16+m)*72 + k0];
      acc[t]=__builtin_amdgcn_mfma_f32_16x16x32_bf16(af,bfr,acc[t],0,0,0);
    }
  }
  #pragma unroll
  for(int t=0;t<4;t++){
    float s=0.f,q=0.f;
    #pragma unroll
    for(int rg=0;rg<4;rg++){
      float v=acc[t][rg];
      s+=v; q+=v*v;
      yt[(w*16+kg*4+rg)*72 + t*16+m]=f2bf(v);
    }
    s+=__shfl_xor(s,16); q+=__shfl_xor(q,16);
    s+=__shfl_xor(s,32); q+=__shfl_xor(q,32);
    if(kg==0){ ps[w][t*16+m]=s; qs[w][t*16+m]=q; }
  }
  __syncthreads();
  if(tid<64){
    float s=ps[0][tid]+ps[1][tid]+ps[2][tid]+ps[3][tid];
    float q=qs[0][tid]+qs[1][tid]+qs[2][tid]+qs[3][tid];
    P[(size_t)tid*4096+blockIdx.x]=s;
    P[(size_t)(128+tid)*4096+blockIdx.x]=q;
  }
  for(int e=tid; e<512; e+=256){
    int r=e>>3, c0=(e&7)*8;
    *reinterpret_cast<uint4*>(y0 + ((size_t)base+r)*64 + c0) = *reinterpret_cast<uint4*>(&yt[r*72+c0]);
  }
}

// ---------------- mid layers via MFMA, ss preloaded to LDS ----------
template<int CIN,int COUT>
__global__ __launch_bounds__(256) void lmid_mfma(const __hip_bfloat16* __restrict__ xin,
    const float* __restrict__ ssIn, const float* __restrict__ W, const float* __restrict__ bias,
    __hip_bfloat16* __restrict__ yout, float* __restrict__ P){
  constexpr int XS = CIN+8;
  constexpr int YS = COUT+8;
  constexpr int NT = COUT/16;
  __shared__ unsigned short xt[64*XS];
  __shared__ unsigned short wt[COUT*XS];
  __shared__ unsigned short yt[64*YS];
  __shared__ float ps[4][COUT];
  __shared__ float qs[4][COUT];
  __shared__ float ssl[256];
  int tid=threadIdx.x; size_t base=(size_t)blockIdx.x*64;
  int w=tid>>6, lane=tid&63;
  ssl[tid]=ssIn[tid];
  __syncthreads();
  for(int e=tid; e<64*CIN/8; e+=256){
    int r=e/(CIN/8), c0=(e%(CIN/8))*8;
    uint4 raw = *reinterpret_cast<const uint4*>(xin + (base+(size_t)r)*CIN + c0);
    unsigned u[4]={raw.x,raw.y,raw.z,raw.w};
    unsigned short* dst=&xt[r*XS+c0];
    #pragma unroll
    for(int k2=0;k2<4;k2++){
      int c=c0+2*k2;
      float lo=__uint_as_float(u[k2]<<16);
      float hi=__uint_as_float(u[k2]&0xFFFF0000u);
      float a=lo*ssl[c]+ssl[128+c]; a=a>0.f?a:0.f;
      float bq=hi*ssl[c+1]+ssl[128+c+1]; bq=bq>0.f?bq:0.f;
      dst[2*k2]=f2bf(a); dst[2*k2+1]=f2bf(bq);
    }
  }
  for(int e=tid; e<CIN*COUT; e+=256){
    int k=e/COUT, n=e-k*COUT;
    wt[n*XS+k]=f2bf(W[e]);
  }
  __syncthreads();
  f32x4 acc[NT];
  #pragma unroll
  for(int t=0;t<NT;t++) acc[t]=(f32x4){0.f,0.f,0.f,0.f};
  int m=lane&15, kg=lane>>4;
  #pragma unroll
  for(int ks=0; ks<CIN/32; ks++){
    int k0=ks*32+kg*8;
    bf16x8 af = *(bf16x8*)&xt[(w*16+m)*XS + k0];
    #pragma unroll
    for(int t=0;t<NT;t++){
      bf16x8 bfr = *(bf16x8*)&wt[(t*16+m)*XS + k0];
      acc[t]=__builtin_amdgcn_mfma_f32_16x16x32_bf16(af,bfr,acc[t],0,0,0);
    }
  }
  #pragma unroll
  for(int t=0;t<NT;t++){
    float bv=bias[t*16+m];
    float s=0.f,q=0.f;
    #pragma unroll
    for(int rg=0;rg<4;rg++){
      float v=acc[t][rg]+bv;
      s+=v; q+=v*v;
      yt[(w*16+kg*4+rg)*YS + t*16+m]=f2bf(v);
    }
    s+=__shfl_xor(s,16); q+=__shfl_xor(q,16);
    s+=__shfl_xor(s,32); q+=__shfl_xor(q,32);
    if(kg==0){ ps[w][t*16+m]=s; qs[w][t*16+m]=q; }
  }
  __syncthreads();
  if(tid<COUT){
    float s=ps[0][tid]+ps[1][tid]+ps[2][tid]+ps[3][tid];
    float q=qs[0][tid]+qs[1][tid]+qs[2][tid]+qs[3][tid];
    P[(size_t)tid*4096+blockIdx.x]=s;
    P[(size_t)(128+tid)*4096+blockIdx.x]=q;
  }
  for(int e=tid; e<64*COUT/8; e+=256){
    int r=e/(COUT/8), c0=(e%(COUT/8))*8;
    *reinterpret_cast<uint4*>(yout + (base+(size_t)r)*COUT + c0) = *reinterpret_cast<uint4*>(&yt[r*YS+c0]);
  }
}

// ---------------- finalize stats: scale/shift per channel ----------------
__global__ void fin_kernel(const float* __restrict__ P, const float* __restrict__ gg, const float* __restrict__ be,
                           float* __restrict__ ss){
  int ch=blockIdx.x; int lane=threadIdx.x;
  float s=0.f,q=0.f;
  for(int blk=lane; blk<4096; blk+=64){ s+=P[(size_t)ch*4096+blk]; q+=P[(size_t)(128+ch)*4096+blk]; }
  #pragma unroll
  for(int m=32;m>=1;m>>=1){ s+=__shfl_xor(s,m); q+=__shfl_xor(q,m); }
  if(lane==0){
    const float invNT = 1.0f/262144.0f;
    float mean=s*invNT; float var=q*invNT - mean*mean;
    float scale=gg[ch]/sqrtf(var+1e-3f);
    ss[ch]=scale; ss[128+ch]=be[ch]-mean*scale;
  }
}

// ---------------- finalize stats (layer2) + M = Wq*Wk^T fused ----------------
__global__ void fin2_kernel(const float* __restrict__ P, const float* __restrict__ gg, const float* __restrict__ be,
                            float* __restrict__ ss, const float* __restrict__ Wq, const float* __restrict__ Wk,
                            float* __restrict__ M){
  int ch=blockIdx.x; int lane=threadIdx.x;
  float s=0.f,q=0.f;
  for(int blk=lane; blk<4096; blk+=64){ s+=P[(size_t)ch*4096+blk]; q+=P[(size_t)(128+ch)*4096+blk]; }
  float m0=0.f,m1=0.f,m2=0.f;
  #pragma unroll
  for(int dd=0; dd<2; dd++){
    int d=lane+dd*64;
    float wk=Wk[ch*128+d];
    m0+=Wq[d]*wk; m1+=Wq[128+d]*wk; m2+=Wq[256+d]*wk;
  }
  #pragma unroll
  for(int m=32;m>=1;m>>=1){
    s+=__shfl_xor(s,m); q+=__shfl_xor(q,m);
    m0+=__shfl_xor(m0,m); m1+=__shfl_xor(m1,m); m2+=__shfl_xor(m2,m);
  }
  if(lane==0){
    const float invNT = 1.0f/262144.0f;
    float mean=s*invNT; float var=q*invNT - mean*mean;
    float scale=gg[ch]/sqrtf(var+1e-3f);
    ss[ch]=scale; ss[128+ch]=be[ch]-mean*scale;
    M[ch]=m0; M[128+ch]=m1; M[256+ch]=m2;
  }
}

// ---------------- per-group: bn2+relu, u=center@M, scores, softmax, hbar, out1=hbar@Wv ----
__global__ __launch_bounds__(256) void sh_kernel(const __hip_bfloat16* __restrict__ y2,
    const float* __restrict__ ss2, const float* __restrict__ M, const float* __restrict__ out0,
    const float* __restrict__ Wv, float* __restrict__ out1){
  __shared__ float h[2][32*130];
  __shared__ float uLds[2][128];
  __shared__ float sLds[2][32];
  __shared__ float partLds[2][4][32];
  __shared__ float ssl[256];
  __shared__ float hbL[2][128];
  int tid=threadIdx.x; int grp=tid>>7, t=tid&127;
  size_t g=(size_t)blockIdx.x*2+grp;
  ssl[tid]=ss2[tid];
  __syncthreads();
  #pragma unroll
  for(int i=0;i<4;i++){
    int e=i*128+t;
    int row=e>>4, c0=(e&15)*8;
    uint4 raw=*reinterpret_cast<const uint4*>(y2+(g*32+(size_t)row)*128+c0);
    unsigned u[4]={raw.x,raw.y,raw.z,raw.w};
    #pragma unroll
    for(int k=0;k<4;k++){
      int c=c0+2*k;
      float lo=__uint_as_float(u[k]<<16), hi=__uint_as_float(u[k]&0xFFFF0000u);
      float a=lo*ssl[c]+ssl[128+c]; float bq=hi*ssl[c+1]+ssl[128+c+1];
      h[grp][row*130+c]  = a>0.f?a:0.f;
      h[grp][row*130+c+1]= bq>0.f?bq:0.f;
    }
  }
  float cx=out0[g*3], cy=out0[g*3+1], cz=out0[g*3+2];
  uLds[grp][t]=cx*M[t]+cy*M[128+t]+cz*M[256+t];
  __syncthreads();
  {
    int row=t&31, q=t>>5;
    float sc=0.f;
    const float* hr=&h[grp][row*130];
    const float* ur=&uLds[grp][0];
    #pragma unroll
    for(int c=0;c<32;c++) sc += hr[q*32+c]*ur[q*32+c];
    partLds[grp][q][row]=sc;
  }
  __syncthreads();
  if(t<32){
    float s=(partLds[grp][0][t]+partLds[grp][1][t])+(partLds[grp][2][t]+partLds[grp][3][t]);
    s*=0.08838834764831845f; // 1/sqrt(128)
    float mx=s;
    #pragma unroll
    for(int m=16;m>=1;m>>=1) mx=fmaxf(mx,__shfl_xor(mx,m));
    float p=expf(s-mx);
    float sum=p;
    #pragma unroll
    for(int m=16;m>=1;m>>=1) sum+=__shfl_xor(sum,m);
    sLds[grp][t]=p/sum;
  }
  __syncthreads();
  float hb=0.f;
  for(int k=0;k<32;k++) hb+=sLds[grp][k]*h[grp][k*130+t];
  hbL[grp][t]=hb;
  __syncthreads();
  float acc=0.f;
  #pragma unroll 4
  for(int c=0;c<128;c++) acc += hbL[grp][c]*Wv[c*128+t];
  out1[g*128+t]=acc;
}

extern "C" void kernel_launch(void* const* d_in, const int* in_sizes, int n_in,
                              void* d_out, int out_size, void* d_ws, size_t ws_size,
                              hipStream_t stream){
  (void)in_sizes; (void)n_in; (void)out_size; (void)ws_size;
  const float* xyz=(const float*)d_in[0];
  const float* pts=(const float*)d_in[1];
  const float* W0=(const float*)d_in[2];  const float* b0=(const float*)d_in[3];
  const float* g0=(const float*)d_in[4];  const float* be0=(const float*)d_in[5];
  const float* W1=(const float*)d_in[6];  const float* b1=(const float*)d_in[7];
  const float* g1=(const float*)d_in[8];  const float* be1=(const float*)d_in[9];
  const float* W2=(const float*)d_in[10]; const float* b2=(const float*)d_in[11];
  const float* g2=(const float*)d_in[12]; const float* be2=(const float*)d_in[13];
  const float* Wq=(const float*)d_in[14]; const float* Wk=(const float*)d_in[15];
  const float* Wv=(const float*)d_in[16];
  float* out0=(float*)d_out;
  float* out1=out0 + (size_t)8*1024*3;
  float* out2=out1 + (size_t)8192*128;

  char* ws=(char*)d_ws; size_t off=0;
  int* idxw=(int*)(ws+off);                    off += (size_t)8192*32*4;
  __hip_bfloat16* fa=(__hip_bfloat16*)(ws+off); off += (size_t)262144*64*2;
  __hip_bfloat16* fb=(__hip_bfloat16*)(ws+off); off += (size_t)262144*64*2;
  __hip_bfloat16* fc=(__hip_bfloat16*)(ws+off); off += (size_t)262144*128*2;
  float* P =(float*)(ws+off);                  off += (size_t)256*4096*4;
  float* ss0=(float*)(ws+off);                 off += 256*4;
  float* ss1=(float*)(ws+off);                 off += 256*4;
  float* ss2=(float*)(ws+off);                 off += 256*4;
  float* M =(float*)(ws+off);                  off += 3*128*4 + 128;

  hipLaunchKernelGGL(fps_kernel,   dim3(8),    dim3(256),  0, stream, xyz, out0);
  hipLaunchKernelGGL(ballq_kernel, dim3(2048), dim3(256),  0, stream, xyz, out0, idxw, out2);
  hipLaunchKernelGGL(l0_mfma,      dim3(4096), dim3(256),  0, stream, xyz, pts, out0, idxw, W0, b0, fa, P);
  hipLaunchKernelGGL(fin_kernel,   dim3(64),   dim3(64),   0, stream, P, g0, be0, ss0);
  hipLaunchKernelGGL((lmid_mfma<64,64>),  dim3(4096), dim3(256), 0, stream, fa, ss0, W1, b1, fb, P);
  hipLaunchKernelGGL(fin_kernel,   dim3(64),   dim3(64),   0, stream, P, g1, be1, ss1);
  hipLaunchKernelGGL((lmid_mfma<64,128>), dim3(4096), dim3(256), 0, stream, fb, ss1, W2, b2, fc, P);
  hipLaunchKernelGGL(fin2_kernel,  dim3(128),  dim3(64),   0, stream, P, g2, be2, ss2, Wq, Wk, M);
  hipLaunchKernelGGL(sh_kernel,    dim3(4096), dim3(256),  0, stream, fc, ss2, M, out0, Wv, out1);
}

// Round 13
// 879.264 us; speedup vs baseline: 8.5799x; 1.0056x over previous
//
#include <hip/hip_runtime.h>
#include <hip/hip_bf16.h>

#define DI __device__ __forceinline__

typedef __attribute__((ext_vector_type(8))) short bf16x8;
typedef __attribute__((ext_vector_type(4))) float f32x4;

DI float fmulr(float a, float b){ return __fmul_rn(a,b); }
DI float faddr(float a, float b){ return __fadd_rn(a,b); }
DI float fsubr(float a, float b){ return __fsub_rn(a,b); }
DI float dist2e(float x,float y,float z,float cx,float cy,float cz){
  float dx=fsubr(x,cx), dy=fsubr(y,cy), dz=fsubr(z,cz);
  return faddr(faddr(fmulr(dx,dx),fmulr(dy,dy)),fmulr(dz,dz));
}
DI unsigned short f2bf(float f){ __hip_bfloat16 h=__float2bfloat16(f); return *reinterpret_cast<unsigned short*>(&h); }

// DPP-based wave64 max: row_shr 1/2/4/8 then row_bcast:15, row_bcast:31 -> lane63 holds max.
template<int C> DI float dmax_step(float x){
  int y=__builtin_amdgcn_update_dpp(0, __float_as_int(x), C, 0xF, 0xF, true);
  return fmaxf(x, __int_as_float(y));
}

// ---------------- prep: weight transposes to bf16 (once, not per-block) + M ----------------
__global__ void prep_kernel(const float* __restrict__ W0, const float* __restrict__ W1,
    const float* __restrict__ W2, const float* __restrict__ Wq, const float* __restrict__ Wk,
    unsigned short* __restrict__ Wt0, unsigned short* __restrict__ Wt1,
    unsigned short* __restrict__ Wt2, float* __restrict__ M){
  int tid=threadIdx.x;
  for(int e=tid;e<4096;e+=256){ int n=e>>6,k=e&63; Wt0[n*72+k]=f2bf(W0[(3+k)*64+n]); }
  for(int e=tid;e<4096;e+=256){ int n=e>>6,k=e&63; Wt1[n*72+k]=f2bf(W1[k*64+n]); }
  for(int e=tid;e<8192;e+=256){ int n=e>>6,k=e&63; Wt2[n*72+k]=f2bf(W2[k*128+n]); }
  if(tid<128){
    int c=tid; float m0=0.f,m1=0.f,m2=0.f;
    for(int d=0;d<128;d++){ float wk=Wk[c*128+d]; m0+=Wq[d]*wk; m1+=Wq[128+d]*wk; m2+=Wq[256+d]*wk; }
    M[c]=m0; M[128+c]=m1; M[256+c]=m2;
  }
}

// ---------------- FPS (r5 version, measured 622us — FROZEN) ----------------
__global__ __launch_bounds__(256) void fps_kernel(const float* __restrict__ xyz, float* __restrict__ out0){
  __shared__ float4 sp4[4096];
  float* spf=(float*)sp4;
  int* spi=(int*)sp4;
  int b=blockIdx.x, tid=threadIdx.x;
  const float* xb = xyz + (size_t)b*4096*3;
  for(int e=tid;e<12288;e+=256){
    int p=e/3, c=e-3*p;
    spf[4*p+c]=xb[e];
  }
  __syncthreads();
  float px[16],py[16],pz[16],dist[16];
  int p0 = tid*16;
  #pragma unroll
  for(int j=0;j<16;j++){ float4 r=sp4[p0+j]; px[j]=r.x; py[j]=r.y; pz[j]=r.z; dist[j]=1e10f; }
  int cur=0;
  float4 cc0=sp4[0];
  float cx=cc0.x, cy=cc0.y, cz=cc0.z;
  int w=tid>>6, lane=tid&63;
  int c0s=0,c1s=0,c2s=0,c3s=0;
  float* ob = out0 + (size_t)b*1024*3;
  #pragma unroll 1
  for(int t=0;t<1024;t++){
    bool mine = ((t&255)==tid);
    int hi = t>>8;
    c0s = (mine && hi==0) ? cur : c0s;
    c1s = (mine && hi==1) ? cur : c1s;
    c2s = (mine && hi==2) ? cur : c2s;
    c3s = (mine && hi==3) ? cur : c3s;
    float nd[16];
    #pragma unroll
    for(int j=0;j<16;j++){
      float d=dist2e(px[j],py[j],pz[j],cx,cy,cz);
      float m=fminf(dist[j],d); dist[j]=m; nd[j]=m;
    }
    float a0=fmaxf(nd[0],nd[1]), a1=fmaxf(nd[2],nd[3]), a2=fmaxf(nd[4],nd[5]), a3=fmaxf(nd[6],nd[7]);
    float a4=fmaxf(nd[8],nd[9]), a5=fmaxf(nd[10],nd[11]), a6=fmaxf(nd[12],nd[13]), a7=fmaxf(nd[14],nd[15]);
    float b0=fmaxf(a0,a1), b1=fmaxf(a2,a3), b2=fmaxf(a4,a5), b3=fmaxf(a6,a7);
    float bv=fmaxf(fmaxf(b0,b1),fmaxf(b2,b3));
    unsigned msk=0u;
    #pragma unroll
    for(int j=0;j<16;j++) msk |= (nd[j]==bv) ? (1u<<j) : 0u;
    int bj=__ffs(msk)-1;
    int bi=p0+bj;
    float x=bv;
    x=dmax_step<0x111>(x); x=dmax_step<0x112>(x); x=dmax_step<0x114>(x); x=dmax_step<0x118>(x);
    x=dmax_step<0x142>(x); x=dmax_step<0x143>(x);
    float wv=__int_as_float(__builtin_amdgcn_readlane(__float_as_int(x),63));
    unsigned long long em=__ballot(bv==wv);
    int L=(int)(__ffsll(em)-1);
    int wbi=__builtin_amdgcn_readlane(bi,L);
    int par=t&1;
    if(lane==0){
      spf[4*(par*8+w)+3]=wv;
      spi[4*(par*8+4+w)+3]=wbi;
    }
    __syncthreads();
    float w0=spf[4*(par*8+0)+3], w1=spf[4*(par*8+1)+3], w2=spf[4*(par*8+2)+3], w3=spf[4*(par*8+3)+3];
    int   i0=spi[4*(par*8+4)+3], i1=spi[4*(par*8+5)+3], i2=spi[4*(par*8+6)+3], i3=spi[4*(par*8+7)+3];
    float mv=fmaxf(fmaxf(w0,w1),fmaxf(w2,w3));
    int u0=(w0==mv)?i0:0x7fffffff, u1=(w1==mv)?i1:0x7fffffff;
    int u2=(w2==mv)?i2:0x7fffffff, u3=(w3==mv)?i3:0x7fffffff;
    cur=min(min(u0,u1),min(u2,u3));
    float4 cc=sp4[cur]; cx=cc.x; cy=cc.y; cz=cc.z;
  }
  { int t0=tid;     float4 c=sp4[c0s]; ob[t0*3]=c.x; ob[t0*3+1]=c.y; ob[t0*3+2]=c.z; }
  { int t1=tid+256; float4 c=sp4[c1s]; ob[t1*3]=c.x; ob[t1*3+1]=c.y; ob[t1*3+2]=c.z; }
  { int t2=tid+512; float4 c=sp4[c2s]; ob[t2*3]=c.x; ob[t2*3+1]=c.y; ob[t2*3+2]=c.z; }
  { int t3=tid+768; float4 c=sp4[c3s]; ob[t3*3]=c.x; ob[t3*3+1]=c.y; ob[t3*3+2]=c.z; }
}

// ---------------- ball query: 8 waves/block share one batch staged in LDS ----------------
__global__ __launch_bounds__(512) void ballq_kernel(const float* __restrict__ xyz, const float* __restrict__ out0,
        int* __restrict__ idxw, float* __restrict__ out2){
  __shared__ float sp[12288];
  int tid=threadIdx.x;
  int g = blockIdx.x*8 + (tid>>6);
  int lane = tid&63;
  int b = blockIdx.x>>7;
  const float* xb = xyz + (size_t)b*4096*3;
  const float4* src=(const float4*)xb; float4* dst=(float4*)sp;
  #pragma unroll
  for(int i=0;i<6;i++) dst[i*512+tid]=src[i*512+tid];
  __syncthreads();
  float cx=out0[(size_t)g*3], cy=out0[(size_t)g*3+1], cz=out0[(size_t)g*3+2];
  const float R2 = (float)(0.2*0.2);
  int cnt=0, firstp=0; bool haveFirst=false;
  for(int c=0;c<64;c++){
    int p=c*64+lane;
    float x=sp[3*p], y=sp[3*p+1], z=sp[3*p+2];
    float d2=dist2e(x,y,z,cx,cy,cz);
    bool inb = d2 < R2;
    unsigned long long mask=__ballot(inb);
    if(!haveFirst && mask){ firstp = c*64 + (__ffsll((unsigned long long)mask)-1); haveFirst=true; }
    int pos = cnt + (int)__popcll(mask & ((1ull<<lane)-1ull));
    if(inb && pos<32){ idxw[(size_t)g*32+pos]=p; out2[(size_t)g*32+pos]=(float)p; }
    cnt += (int)__popcll(mask);
    if(cnt>=32) break;
  }
  if(cnt<32){
    for(int j=cnt+lane; j<32; j+=64){ idxw[(size_t)g*32+j]=firstp; out2[(size_t)g*32+j]=(float)firstp; }
  }
}

// ---------------- layer0 via MFMA: gather->bf16, K=64 MFMA + scalar xyz part ----------
__global__ __launch_bounds__(256) void l0_mfma(const float* __restrict__ xyz, const float* __restrict__ pts,
    const float* __restrict__ out0, const int* __restrict__ idxw,
    const float* __restrict__ W0, const float* __restrict__ b0,
    const unsigned short* __restrict__ Wt0,
    __hip_bfloat16* __restrict__ y0, float* __restrict__ P){
  __shared__ unsigned short xg[64*72];
  __shared__ unsigned short wt[64*72];
  __shared__ unsigned short yt[64*72];
  __shared__ float xyzl[64][4];
  __shared__ float w0c[3][64];
  __shared__ float ps[4][64];
  __shared__ float qs[4][64];
  int tid=threadIdx.x; int base=blockIdx.x*64;
  int w=tid>>6, lane=tid&63;
  for(int i=0;i<16;i++){
    int r=w*16+i; int R=base+r;
    int g=R>>5; int b=g>>10; int p=idxw[R];
    xg[r*72+lane] = f2bf(pts[((size_t)b*4096+(size_t)p)*64+lane]);
    if(lane<3) xyzl[r][lane] = fsubr(xyz[((size_t)b*4096+(size_t)p)*3+lane], out0[(size_t)g*3+lane]);
  }
  for(int e=tid; e<576; e+=256) ((uint4*)wt)[e]=((const uint4*)Wt0)[e];
  if(tid<192){ int r=tid>>6, n=tid&63; w0c[r][n]=W0[r*64+n]; }
  __syncthreads();
  int m=lane&15, kg=lane>>4;
  f32x4 acc[4];
  #pragma unroll
  for(int t=0;t<4;t++){
    int col=t*16+m;
    float bb=b0[col], wx=w0c[0][col], wy=w0c[1][col], wz=w0c[2][col];
    #pragma unroll
    for(int rg=0;rg<4;rg++){
      int row=w*16+kg*4+rg;
      acc[t][rg]=bb + xyzl[row][0]*wx + xyzl[row][1]*wy + xyzl[row][2]*wz;
    }
  }
  #pragma unroll
  for(int ks=0; ks<2; ks++){
    int k0=ks*32+kg*8;
    bf16x8 af = *(bf16x8*)&xg[(w*16+m)*72 + k0];
    #pragma unroll
    for(int t=0;t<4;t++){
      bf16x8 bfr = *(bf16x8*)&wt[(t*16+m)*72 + k0];
      acc[t]=__builtin_amdgcn_mfma_f32_16x16x32_bf16(af,bfr,acc[t],0,0,0);
    }
  }
  #pragma unroll
  for(int t=0;t<4;t++){
    float s=0.f,q=0.f;
    #pragma unroll
    for(int rg=0;rg<4;rg++){
      float v=acc[t][rg];
      s+=v; q+=v*v;
      yt[(w*16+kg*4+rg)*72 + t*16+m]=f2bf(v);
    }
    s+=__shfl_xor(s,16); q+=__shfl_xor(q,16);
    s+=__shfl_xor(s,32); q+=__shfl_xor(q,32);
    if(kg==0){ ps[w][t*16+m]=s; qs[w][t*16+m]=q; }
  }
  __syncthreads();
  if(tid<64){
    float s=ps[0][tid]+ps[1][tid]+ps[2][tid]+ps[3][tid];
    float q=qs[0][tid]+qs[1][tid]+qs[2][tid]+qs[3][tid];
    P[(size_t)tid*4096+blockIdx.x]=s;
    P[(size_t)(128+tid)*4096+blockIdx.x]=q;
  }
  for(int e=tid; e<512; e+=256){
    int r=e>>3, c0=(e&7)*8;
    *reinterpret_cast<uint4*>(y0 + ((size_t)base+r)*64 + c0) = *reinterpret_cast<uint4*>(&yt[r*72+c0]);
  }
}

// ---------------- mid layers via MFMA, precomputed bf16 W^T, ss in LDS ----------
template<int CIN,int COUT>
__global__ __launch_bounds__(256) void lmid_mfma(const __hip_bfloat16* __restrict__ xin,
    const float* __restrict__ ssIn, const unsigned short* __restrict__ Wt,
    const float* __restrict__ bias,
    __hip_bfloat16* __restrict__ yout, float* __restrict__ P){
  constexpr int XS = CIN+8;
  constexpr int YS = COUT+8;
  constexpr int NT = COUT/16;
  __shared__ unsigned short xt[64*XS];
  __shared__ unsigned short wt[COUT*XS];
  __shared__ unsigned short yt[64*YS];
  __shared__ float ps[4][COUT];
  __shared__ float qs[4][COUT];
  __shared__ float ssl[256];
  int tid=threadIdx.x; size_t base=(size_t)blockIdx.x*64;
  int w=tid>>6, lane=tid&63;
  ssl[tid]=ssIn[tid];
  for(int e=tid; e<COUT*9; e+=256) ((uint4*)wt)[e]=((const uint4*)Wt)[e];
  __syncthreads();
  for(int e=tid; e<64*CIN/8; e+=256){
    int r=e/(CIN/8), c0=(e%(CIN/8))*8;
    uint4 raw = *reinterpret_cast<const uint4*>(xin + (base+(size_t)r)*CIN + c0);
    unsigned u[4]={raw.x,raw.y,raw.z,raw.w};
    unsigned short* dst=&xt[r*XS+c0];
    #pragma unroll
    for(int k2=0;k2<4;k2++){
      int c=c0+2*k2;
      float lo=__uint_as_float(u[k2]<<16);
      float hi=__uint_as_float(u[k2]&0xFFFF0000u);
      float a=lo*ssl[c]+ssl[128+c]; a=a>0.f?a:0.f;
      float bq=hi*ssl[c+1]+ssl[128+c+1]; bq=bq>0.f?bq:0.f;
      dst[2*k2]=f2bf(a); dst[2*k2+1]=f2bf(bq);
    }
  }
  __syncthreads();
  f32x4 acc[NT];
  #pragma unroll
  for(int t=0;t<NT;t++) acc[t]=(f32x4){0.f,0.f,0.f,0.f};
  int m=lane&15, kg=lane>>4;
  #pragma unroll
  for(int ks=0; ks<CIN/32; ks++){
    int k0=ks*32+kg*8;
    bf16x8 af = *(bf16x8*)&xt[(w*16+m)*XS + k0];
    #pragma unroll
    for(int t=0;t<NT;t++){
      bf16x8 bfr = *(bf16x8*)&wt[(t*16+m)*XS + k0];
      acc[t]=__builtin_amdgcn_mfma_f32_16x16x32_bf16(af,bfr,acc[t],0,0,0);
    }
  }
  #pragma unroll
  for(int t=0;t<NT;t++){
    float bv=bias[t*16+m];
    float s=0.f,q=0.f;
    #pragma unroll
    for(int rg=0;rg<4;rg++){
      float v=acc[t][rg]+bv;
      s+=v; q+=v*v;
      yt[(w*16+kg*4+rg)*YS + t*16+m]=f2bf(v);
    }
    s+=__shfl_xor(s,16); q+=__shfl_xor(q,16);
    s+=__shfl_xor(s,32); q+=__shfl_xor(q,32);
    if(kg==0){ ps[w][t*16+m]=s; qs[w][t*16+m]=q; }
  }
  __syncthreads();
  if(tid<COUT){
    float s=ps[0][tid]+ps[1][tid]+ps[2][tid]+ps[3][tid];
    float q=qs[0][tid]+qs[1][tid]+qs[2][tid]+qs[3][tid];
    P[(size_t)tid*4096+blockIdx.x]=s;
    P[(size_t)(128+tid)*4096+blockIdx.x]=q;
  }
  for(int e=tid; e<64*COUT/8; e+=256){
    int r=e/(COUT/8), c0=(e%(COUT/8))*8;
    *reinterpret_cast<uint4*>(yout + (base+(size_t)r)*COUT + c0) = *reinterpret_cast<uint4*>(&yt[r*YS+c0]);
  }
}

// ---------------- finalize stats: scale/shift per channel ----------------
__global__ void fin_kernel(const float* __restrict__ P, const float* __restrict__ gg, const float* __restrict__ be,
                           float* __restrict__ ss){
  int ch=blockIdx.x; int lane=threadIdx.x;
  float s=0.f,q=0.f;
  for(int blk=lane; blk<4096; blk+=64){ s+=P[(size_t)ch*4096+blk]; q+=P[(size_t)(128+ch)*4096+blk]; }
  #pragma unroll
  for(int m=32;m>=1;m>>=1){ s+=__shfl_xor(s,m); q+=__shfl_xor(q,m); }
  if(lane==0){
    const float invNT = 1.0f/262144.0f;
    float mean=s*invNT; float var=q*invNT - mean*mean;
    float scale=gg[ch]/sqrtf(var+1e-3f);
    ss[ch]=scale; ss[128+ch]=be[ch]-mean*scale;
  }
}

// ---------------- per-group: bn2+relu, u=center@M, scores, softmax, hbar, out1=hbar@Wv ----
__global__ __launch_bounds__(256) void sh_kernel(const __hip_bfloat16* __restrict__ y2,
    const float* __restrict__ ss2, const float* __restrict__ M, const float* __restrict__ out0,
    const float* __restrict__ Wv, float* __restrict__ out1){
  __shared__ float h[2][32*130];
  __shared__ float uLds[2][128];
  __shared__ float sLds[2][32];
  __shared__ float partLds[2][4][32];
  __shared__ float ssl[256];
  __shared__ float hbL[2][128];
  int tid=threadIdx.x; int grp=tid>>7, t=tid&127;
  size_t g=(size_t)blockIdx.x*2+grp;
  ssl[tid]=ss2[tid];
  __syncthreads();
  #pragma unroll
  for(int i=0;i<4;i++){
    int e=i*128+t;
    int row=e>>4, c0=(e&15)*8;
    uint4 raw=*reinterpret_cast<const uint4*>(y2+(g*32+(size_t)row)*128+c0);
    unsigned u[4]={raw.x,raw.y,raw.z,raw.w};
    #pragma unroll
    for(int k=0;k<4;k++){
      int c=c0+2*k;
      float lo=__uint_as_float(u[k]<<16), hi=__uint_as_float(u[k]&0xFFFF0000u);
      float a=lo*ssl[c]+ssl[128+c]; float bq=hi*ssl[c+1]+ssl[128+c+1];
      h[grp][row*130+c]  = a>0.f?a:0.f;
      h[grp][row*130+c+1]= bq>0.f?bq:0.f;
    }
  }
  float cx=out0[g*3], cy=out0[g*3+1], cz=out0[g*3+2];
  uLds[grp][t]=cx*M[t]+cy*M[128+t]+cz*M[256+t];
  __syncthreads();
  {
    int row=t&31, q=t>>5;
    float sc=0.f;
    const float* hr=&h[grp][row*130];
    const float* ur=&uLds[grp][0];
    #pragma unroll
    for(int c=0;c<32;c++) sc += hr[q*32+c]*ur[q*32+c];
    partLds[grp][q][row]=sc;
  }
  __syncthreads();
  if(t<32){
    float s=(partLds[grp][0][t]+partLds[grp][1][t])+(partLds[grp][2][t]+partLds[grp][3][t]);
    s*=0.08838834764831845f; // 1/sqrt(128)
    float mx=s;
    #pragma unroll
    for(int m=16;m>=1;m>>=1) mx=fmaxf(mx,__shfl_xor(mx,m));
    float p=expf(s-mx);
    float sum=p;
    #pragma unroll
    for(int m=16;m>=1;m>>=1) sum+=__shfl_xor(sum,m);
    sLds[grp][t]=p/sum;
  }
  __syncthreads();
  float hb=0.f;
  for(int k=0;k<32;k++) hb+=sLds[grp][k]*h[grp][k*130+t];
  hbL[grp][t]=hb;
  __syncthreads();
  float acc=0.f;
  #pragma unroll 4
  for(int c=0;c<128;c++) acc += hbL[grp][c]*Wv[c*128+t];
  out1[g*128+t]=acc;
}

extern "C" void kernel_launch(void* const* d_in, const int* in_sizes, int n_in,
                              void* d_out, int out_size, void* d_ws, size_t ws_size,
                              hipStream_t stream){
  (void)in_sizes; (void)n_in; (void)out_size; (void)ws_size;
  const float* xyz=(const float*)d_in[0];
  const float* pts=(const float*)d_in[1];
  const float* W0=(const float*)d_in[2];  const float* b0=(const float*)d_in[3];
  const float* g0=(const float*)d_in[4];  const float* be0=(const float*)d_in[5];
  const float* W1=(const float*)d_in[6];  const float* b1=(const float*)d_in[7];
  const float* g1=(const float*)d_in[8];  const float* be1=(const float*)d_in[9];
  const float* W2=(const float*)d_in[10]; const float* b2=(const float*)d_in[11];
  const float* g2=(const float*)d_in[12]; const float* be2=(const float*)d_in[13];
  const float* Wq=(const float*)d_in[14]; const float* Wk=(const float*)d_in[15];
  const float* Wv=(const float*)d_in[16];
  float* out0=(float*)d_out;
  float* out1=out0 + (size_t)8*1024*3;
  float* out2=out1 + (size_t)8192*128;

  char* ws=(char*)d_ws; size_t off=0;
  int* idxw=(int*)(ws+off);                    off += (size_t)8192*32*4;
  __hip_bfloat16* fa=(__hip_bfloat16*)(ws+off); off += (size_t)262144*64*2;
  __hip_bfloat16* fb=(__hip_bfloat16*)(ws+off); off += (size_t)262144*64*2;
  __hip_bfloat16* fc=(__hip_bfloat16*)(ws+off); off += (size_t)262144*128*2;
  float* P =(float*)(ws+off);                  off += (size_t)256*4096*4;
  float* ss0=(float*)(ws+off);                 off += 256*4;
  float* ss1=(float*)(ws+off);                 off += 256*4;
  float* ss2=(float*)(ws+off);                 off += 256*4;
  float* M =(float*)(ws+off);                  off += 3*128*4 + 128;
  unsigned short* Wt0=(unsigned short*)(ws+off); off += (size_t)64*72*2;
  unsigned short* Wt1=(unsigned short*)(ws+off); off += (size_t)64*72*2;
  unsigned short* Wt2=(unsigned short*)(ws+off); off += (size_t)128*72*2;

  hipLaunchKernelGGL(prep_kernel,  dim3(1),    dim3(256),  0, stream, W0, W1, W2, Wq, Wk, Wt0, Wt1, Wt2, M);
  hipLaunchKernelGGL(fps_kernel,   dim3(8),    dim3(256),  0, stream, xyz, out0);
  hipLaunchKernelGGL(ballq_kernel, dim3(1024), dim3(512),  0, stream, xyz, out0, idxw, out2);
  hipLaunchKernelGGL(l0_mfma,      dim3(4096), dim3(256),  0, stream, xyz, pts, out0, idxw, W0, b0, Wt0, fa, P);
  hipLaunchKernelGGL(fin_kernel,   dim3(64),   dim3(64),   0, stream, P, g0, be0, ss0);
  hipLaunchKernelGGL((lmid_mfma<64,64>),  dim3(4096), dim3(256), 0, stream, fa, ss0, Wt1, b1, fb, P);
  hipLaunchKernelGGL(fin_kernel,   dim3(64),   dim3(64),   0, stream, P, g1, be1, ss1);
  hipLaunchKernelGGL((lmid_mfma<64,128>), dim3(4096), dim3(256), 0, stream, fb, ss1, Wt2, b2, fc, P);
  hipLaunchKernelGGL(fin_kernel,   dim3(128),  dim3(64),   0, stream, P, g2, be2, ss2);
  hipLaunchKernelGGL(sh_kernel,    dim3(4096), dim3(256),  0, stream, fc, ss2, M, out0, Wv, out1);
}

// Round 14
// 858.082 us; speedup vs baseline: 8.7917x; 1.0247x over previous
//
#include <hip/hip_runtime.h>
#include <hip/hip_bf16.h>

#define DI __device__ __forceinline__

typedef float v2f __attribute__((ext_vector_type(2)));
typedef __attribute__((ext_vector_type(8))) short bf16x8;
typedef __attribute__((ext_vector_type(4))) float f32x4;

DI float fmulr(float a, float b){ return __fmul_rn(a,b); }
DI float faddr(float a, float b){ return __fadd_rn(a,b); }
DI float fsubr(float a, float b){ return __fsub_rn(a,b); }
DI float dist2e(float x,float y,float z,float cx,float cy,float cz){
  float dx=fsubr(x,cx), dy=fsubr(y,cy), dz=fsubr(z,cz);
  return faddr(faddr(fmulr(dx,dx),fmulr(dy,dy)),fmulr(dz,dz));
}
DI unsigned short f2bf(float f){ __hip_bfloat16 h=__float2bfloat16(f); return *reinterpret_cast<unsigned short*>(&h); }

// DPP-based wave64 max: row_shr 1/2/4/8 then row_bcast:15, row_bcast:31 -> lane63 holds max.
template<int C> DI float dmax_step(float x){
  int y=__builtin_amdgcn_update_dpp(0, __float_as_int(x), C, 0xF, 0xF, true);
  return fmaxf(x, __int_as_float(y));
}

// ---------------- prep: weight transposes to bf16 (once, not per-block) + M ----------------
__global__ void prep_kernel(const float* __restrict__ W0, const float* __restrict__ W1,
    const float* __restrict__ W2, const float* __restrict__ Wq, const float* __restrict__ Wk,
    unsigned short* __restrict__ Wt0, unsigned short* __restrict__ Wt1,
    unsigned short* __restrict__ Wt2, float* __restrict__ M){
  int tid=threadIdx.x;
  for(int e=tid;e<4096;e+=256){ int n=e>>6,k=e&63; Wt0[n*72+k]=f2bf(W0[(3+k)*64+n]); }
  for(int e=tid;e<4096;e+=256){ int n=e>>6,k=e&63; Wt1[n*72+k]=f2bf(W1[k*64+n]); }
  for(int e=tid;e<8192;e+=256){ int n=e>>6,k=e&63; Wt2[n*72+k]=f2bf(W2[k*128+n]); }
  if(tid<128){
    int c=tid; float m0=0.f,m1=0.f,m2=0.f;
    for(int d=0;d<128;d++){ float wk=Wk[c*128+d]; m0+=Wq[d]*wk; m1+=Wq[128+d]*wk; m2+=Wq[256+d]*wk; }
    M[c]=m0; M[128+c]=m1; M[256+c]=m2;
  }
}

// ---------------- FPS: r5 structure (frozen exchange) + packed-fp32 dist/tree ----------------
// Packed per-component IEEE rn == scalar (r6-proven bit-exact, contract off). Mask reads
// packed components in index order (bits 2j/2j+1) -> identical first-occurrence tie-break.
__global__ __launch_bounds__(256) void fps_kernel(const float* __restrict__ xyz, float* __restrict__ out0){
  __shared__ float4 sp4[4096];
  float* spf=(float*)sp4;
  int* spi=(int*)sp4;
  int b=blockIdx.x, tid=threadIdx.x;
  const float* xb = xyz + (size_t)b*4096*3;
  for(int e=tid;e<12288;e+=256){
    int p=e/3, c=e-3*p;
    spf[4*p+c]=xb[e];
  }
  __syncthreads();
  v2f px[8],py[8],pz[8],dist[8];
  int p0 = tid*16;
  #pragma unroll
  for(int j=0;j<8;j++){
    float4 r0=sp4[p0+2*j], r1=sp4[p0+2*j+1];
    px[j]=(v2f){r0.x,r1.x}; py[j]=(v2f){r0.y,r1.y}; pz[j]=(v2f){r0.z,r1.z};
    dist[j]=(v2f){1e10f,1e10f};
  }
  int cur=0;
  float4 cc0=sp4[0];
  float cx=cc0.x, cy=cc0.y, cz=cc0.z;
  int w=tid>>6, lane=tid&63;
  int c0s=0,c1s=0,c2s=0,c3s=0;
  float* ob = out0 + (size_t)b*1024*3;
  #pragma unroll 1
  for(int t=0;t<1024;t++){
    bool mine = ((t&255)==tid);
    int hi = t>>8;
    c0s = (mine && hi==0) ? cur : c0s;
    c1s = (mine && hi==1) ? cur : c1s;
    c2s = (mine && hi==2) ? cur : c2s;
    c3s = (mine && hi==3) ? cur : c3s;
    v2f nd[8];
    {
      #pragma clang fp contract(off)
      v2f c2x={cx,cx}, c2y={cy,cy}, c2z={cz,cz};
      #pragma unroll
      for(int j=0;j<8;j++){
        v2f dx=px[j]-c2x, dy=py[j]-c2y, dz=pz[j]-c2z;
        v2f dd=(dx*dx+dy*dy)+dz*dz;
        v2f nm=__builtin_elementwise_min(dist[j],dd);
        dist[j]=nm; nd[j]=nm;
      }
    }
    v2f e0=__builtin_elementwise_max(nd[0],nd[1]);
    v2f e1=__builtin_elementwise_max(nd[2],nd[3]);
    v2f e2=__builtin_elementwise_max(nd[4],nd[5]);
    v2f e3=__builtin_elementwise_max(nd[6],nd[7]);
    v2f f0=__builtin_elementwise_max(e0,e1);
    v2f f1=__builtin_elementwise_max(e2,e3);
    v2f g =__builtin_elementwise_max(f0,f1);
    float bv=fmaxf(g.x,g.y);
    unsigned msk=0u;
    #pragma unroll
    for(int j=0;j<8;j++){
      msk |= (nd[j].x==bv)?(1u<<(2*j)):0u;
      msk |= (nd[j].y==bv)?(1u<<(2*j+1)):0u;
    }
    int bj=__ffs(msk)-1;
    int bi=p0+bj;
    float x=bv;
    x=dmax_step<0x111>(x); x=dmax_step<0x112>(x); x=dmax_step<0x114>(x); x=dmax_step<0x118>(x);
    x=dmax_step<0x142>(x); x=dmax_step<0x143>(x);
    float wv=__int_as_float(__builtin_amdgcn_readlane(__float_as_int(x),63));
    unsigned long long em=__ballot(bv==wv);
    int L=(int)(__ffsll(em)-1);
    int wbi=__builtin_amdgcn_readlane(bi,L);
    int par=t&1;
    if(lane==0){
      spf[4*(par*8+w)+3]=wv;
      spi[4*(par*8+4+w)+3]=wbi;
    }
    __syncthreads();
    float w0=spf[4*(par*8+0)+3], w1=spf[4*(par*8+1)+3], w2=spf[4*(par*8+2)+3], w3=spf[4*(par*8+3)+3];
    int   i0=spi[4*(par*8+4)+3], i1=spi[4*(par*8+5)+3], i2=spi[4*(par*8+6)+3], i3=spi[4*(par*8+7)+3];
    float mv=fmaxf(fmaxf(w0,w1),fmaxf(w2,w3));
    int u0=(w0==mv)?i0:0x7fffffff, u1=(w1==mv)?i1:0x7fffffff;
    int u2=(w2==mv)?i2:0x7fffffff, u3=(w3==mv)?i3:0x7fffffff;
    cur=min(min(u0,u1),min(u2,u3));
    float4 cc=sp4[cur]; cx=cc.x; cy=cc.y; cz=cc.z;
  }
  { int t0=tid;     float4 c=sp4[c0s]; ob[t0*3]=c.x; ob[t0*3+1]=c.y; ob[t0*3+2]=c.z; }
  { int t1=tid+256; float4 c=sp4[c1s]; ob[t1*3]=c.x; ob[t1*3+1]=c.y; ob[t1*3+2]=c.z; }
  { int t2=tid+512; float4 c=sp4[c2s]; ob[t2*3]=c.x; ob[t2*3+1]=c.y; ob[t2*3+2]=c.z; }
  { int t3=tid+768; float4 c=sp4[c3s]; ob[t3*3]=c.x; ob[t3*3+1]=c.y; ob[t3*3+2]=c.z; }
}

// ---------------- ball query: 8 waves/block share one batch staged in LDS ----------------
__global__ __launch_bounds__(512) void ballq_kernel(const float* __restrict__ xyz, const float* __restrict__ out0,
        int* __restrict__ idxw, float* __restrict__ out2){
  __shared__ float sp[12288];
  int tid=threadIdx.x;
  int g = blockIdx.x*8 + (tid>>6);
  int lane = tid&63;
  int b = blockIdx.x>>7;
  const float* xb = xyz + (size_t)b*4096*3;
  const float4* src=(const float4*)xb; float4* dst=(float4*)sp;
  #pragma unroll
  for(int i=0;i<6;i++) dst[i*512+tid]=src[i*512+tid];
  __syncthreads();
  float cx=out0[(size_t)g*3], cy=out0[(size_t)g*3+1], cz=out0[(size_t)g*3+2];
  const float R2 = (float)(0.2*0.2);
  int cnt=0, firstp=0; bool haveFirst=false;
  for(int c=0;c<64;c++){
    int p=c*64+lane;
    float x=sp[3*p], y=sp[3*p+1], z=sp[3*p+2];
    float d2=dist2e(x,y,z,cx,cy,cz);
    bool inb = d2 < R2;
    unsigned long long mask=__ballot(inb);
    if(!haveFirst && mask){ firstp = c*64 + (__ffsll((unsigned long long)mask)-1); haveFirst=true; }
    int pos = cnt + (int)__popcll(mask & ((1ull<<lane)-1ull));
    if(inb && pos<32){ idxw[(size_t)g*32+pos]=p; out2[(size_t)g*32+pos]=(float)p; }
    cnt += (int)__popcll(mask);
    if(cnt>=32) break;
  }
  if(cnt<32){
    for(int j=cnt+lane; j<32; j+=64){ idxw[(size_t)g*32+j]=firstp; out2[(size_t)g*32+j]=(float)firstp; }
  }
}

// ---------------- layer0 via MFMA: gather->bf16, K=64 MFMA + scalar xyz part ----------
__global__ __launch_bounds__(256) void l0_mfma(const float* __restrict__ xyz, const float* __restrict__ pts,
    const float* __restrict__ out0, const int* __restrict__ idxw,
    const float* __restrict__ W0, const float* __restrict__ b0,
    const unsigned short* __restrict__ Wt0,
    __hip_bfloat16* __restrict__ y0, float* __restrict__ P){
  __shared__ unsigned short xg[64*72];
  __shared__ unsigned short wt[64*72];
  __shared__ unsigned short yt[64*72];
  __shared__ float xyzl[64][4];
  __shared__ float w0c[3][64];
  __shared__ float ps[4][64];
  __shared__ float qs[4][64];
  int tid=threadIdx.x; int base=blockIdx.x*64;
  int w=tid>>6, lane=tid&63;
  for(int i=0;i<16;i++){
    int r=w*16+i; int R=base+r;
    int g=R>>5; int b=g>>10; int p=idxw[R];
    xg[r*72+lane] = f2bf(pts[((size_t)b*4096+(size_t)p)*64+lane]);
    if(lane<3) xyzl[r][lane] = fsubr(xyz[((size_t)b*4096+(size_t)p)*3+lane], out0[(size_t)g*3+lane]);
  }
  for(int e=tid; e<576; e+=256) ((uint4*)wt)[e]=((const uint4*)Wt0)[e];
  if(tid<192){ int r=tid>>6, n=tid&63; w0c[r][n]=W0[r*64+n]; }
  __syncthreads();
  int m=lane&15, kg=lane>>4;
  f32x4 acc[4];
  #pragma unroll
  for(int t=0;t<4;t++){
    int col=t*16+m;
    float bb=b0[col], wx=w0c[0][col], wy=w0c[1][col], wz=w0c[2][col];
    #pragma unroll
    for(int rg=0;rg<4;rg++){
      int row=w*16+kg*4+rg;
      acc[t][rg]=bb + xyzl[row][0]*wx + xyzl[row][1]*wy + xyzl[row][2]*wz;
    }
  }
  #pragma unroll
  for(int ks=0; ks<2; ks++){
    int k0=ks*32+kg*8;
    bf16x8 af = *(bf16x8*)&xg[(w*16+m)*72 + k0];
    #pragma unroll
    for(int t=0;t<4;t++){
      bf16x8 bfr = *(bf16x8*)&wt[(t*16+m)*72 + k0];
      acc[t]=__builtin_amdgcn_mfma_f32_16x16x32_bf16(af,bfr,acc[t],0,0,0);
    }
  }
  #pragma unroll
  for(int t=0;t<4;t++){
    float s=0.f,q=0.f;
    #pragma unroll
    for(int rg=0;rg<4;rg++){
      float v=acc[t][rg];
      s+=v; q+=v*v;
      yt[(w*16+kg*4+rg)*72 + t*16+m]=f2bf(v);
    }
    s+=__shfl_xor(s,16); q+=__shfl_xor(q,16);
    s+=__shfl_xor(s,32); q+=__shfl_xor(q,32);
    if(kg==0){ ps[w][t*16+m]=s; qs[w][t*16+m]=q; }
  }
  __syncthreads();
  if(tid<64){
    float s=ps[0][tid]+ps[1][tid]+ps[2][tid]+ps[3][tid];
    float q=qs[0][tid]+qs[1][tid]+qs[2][tid]+qs[3][tid];
    P[(size_t)tid*4096+blockIdx.x]=s;
    P[(size_t)(128+tid)*4096+blockIdx.x]=q;
  }
  for(int e=tid; e<512; e+=256){
    int r=e>>3, c0=(e&7)*8;
    *reinterpret_cast<uint4*>(y0 + ((size_t)base+r)*64 + c0) = *reinterpret_cast<uint4*>(&yt[r*72+c0]);
  }
}

// ---------------- mid layers via MFMA, precomputed bf16 W^T, ss in LDS ----------
template<int CIN,int COUT>
__global__ __launch_bounds__(256) void lmid_mfma(const __hip_bfloat16* __restrict__ xin,
    const float* __restrict__ ssIn, const unsigned short* __restrict__ Wt,
    const float* __restrict__ bias,
    __hip_bfloat16* __restrict__ yout, float* __restrict__ P){
  constexpr int XS = CIN+8;
  constexpr int YS = COUT+8;
  constexpr int NT = COUT/16;
  __shared__ unsigned short xt[64*XS];
  __shared__ unsigned short wt[COUT*XS];
  __shared__ unsigned short yt[64*YS];
  __shared__ float ps[4][COUT];
  __shared__ float qs[4][COUT];
  __shared__ float ssl[256];
  int tid=threadIdx.x; size_t base=(size_t)blockIdx.x*64;
  int w=tid>>6, lane=tid&63;
  ssl[tid]=ssIn[tid];
  for(int e=tid; e<COUT*9; e+=256) ((uint4*)wt)[e]=((const uint4*)Wt)[e];
  __syncthreads();
  for(int e=tid; e<64*CIN/8; e+=256){
    int r=e/(CIN/8), c0=(e%(CIN/8))*8;
    uint4 raw = *reinterpret_cast<const uint4*>(xin + (base+(size_t)r)*CIN + c0);
    unsigned u[4]={raw.x,raw.y,raw.z,raw.w};
    unsigned short* dst=&xt[r*XS+c0];
    #pragma unroll
    for(int k2=0;k2<4;k2++){
      int c=c0+2*k2;
      float lo=__uint_as_float(u[k2]<<16);
      float hi=__uint_as_float(u[k2]&0xFFFF0000u);
      float a=lo*ssl[c]+ssl[128+c]; a=a>0.f?a:0.f;
      float bq=hi*ssl[c+1]+ssl[128+c+1]; bq=bq>0.f?bq:0.f;
      dst[2*k2]=f2bf(a); dst[2*k2+1]=f2bf(bq);
    }
  }
  __syncthreads();
  f32x4 acc[NT];
  #pragma unroll
  for(int t=0;t<NT;t++) acc[t]=(f32x4){0.f,0.f,0.f,0.f};
  int m=lane&15, kg=lane>>4;
  #pragma unroll
  for(int ks=0; ks<CIN/32; ks++){
    int k0=ks*32+kg*8;
    bf16x8 af = *(bf16x8*)&xt[(w*16+m)*XS + k0];
    #pragma unroll
    for(int t=0;t<NT;t++){
      bf16x8 bfr = *(bf16x8*)&wt[(t*16+m)*XS + k0];
      acc[t]=__builtin_amdgcn_mfma_f32_16x16x32_bf16(af,bfr,acc[t],0,0,0);
    }
  }
  #pragma unroll
  for(int t=0;t<NT;t++){
    float bv=bias[t*16+m];
    float s=0.f,q=0.f;
    #pragma unroll
    for(int rg=0;rg<4;rg++){
      float v=acc[t][rg]+bv;
      s+=v; q+=v*v;
      yt[(w*16+kg*4+rg)*YS + t*16+m]=f2bf(v);
    }
    s+=__shfl_xor(s,16); q+=__shfl_xor(q,16);
    s+=__shfl_xor(s,32); q+=__shfl_xor(q,32);
    if(kg==0){ ps[w][t*16+m]=s; qs[w][t*16+m]=q; }
  }
  __syncthreads();
  if(tid<COUT){
    float s=ps[0][tid]+ps[1][tid]+ps[2][tid]+ps[3][tid];
    float q=qs[0][tid]+qs[1][tid]+qs[2][tid]+qs[3][tid];
    P[(size_t)tid*4096+blockIdx.x]=s;
    P[(size_t)(128+tid)*4096+blockIdx.x]=q;
  }
  for(int e=tid; e<64*COUT/8; e+=256){
    int r=e/(COUT/8), c0=(e&7)*8;
    *reinterpret_cast<uint4*>(yout + (base+(size_t)r)*COUT + (e%(COUT/8))*8) = *reinterpret_cast<uint4*>(&yt[r*YS+(e%(COUT/8))*8]);
    (void)c0;
  }
}

// ---------------- finalize stats: scale/shift per channel ----------------
__global__ void fin_kernel(const float* __restrict__ P, const float* __restrict__ gg, const float* __restrict__ be,
                           float* __restrict__ ss){
  int ch=blockIdx.x; int lane=threadIdx.x;
  float s=0.f,q=0.f;
  for(int blk=lane; blk<4096; blk+=64){ s+=P[(size_t)ch*4096+blk]; q+=P[(size_t)(128+ch)*4096+blk]; }
  #pragma unroll
  for(int m=32;m>=1;m>>=1){ s+=__shfl_xor(s,m); q+=__shfl_xor(q,m); }
  if(lane==0){
    const float invNT = 1.0f/262144.0f;
    float mean=s*invNT; float var=q*invNT - mean*mean;
    float scale=gg[ch]/sqrtf(var+1e-3f);
    ss[ch]=scale; ss[128+ch]=be[ch]-mean*scale;
  }
}

// ---------------- per-group: bn2+relu, u=center@M, scores, softmax, hbar, out1=hbar@Wv ----
__global__ __launch_bounds__(256) void sh_kernel(const __hip_bfloat16* __restrict__ y2,
    const float* __restrict__ ss2, const float* __restrict__ M, const float* __restrict__ out0,
    const float* __restrict__ Wv, float* __restrict__ out1){
  __shared__ float h[2][32*130];
  __shared__ float uLds[2][128];
  __shared__ float sLds[2][32];
  __shared__ float partLds[2][4][32];
  __shared__ float ssl[256];
  __shared__ float hbL[2][128];
  int tid=threadIdx.x; int grp=tid>>7, t=tid&127;
  size_t g=(size_t)blockIdx.x*2+grp;
  ssl[tid]=ss2[tid];
  __syncthreads();
  #pragma unroll
  for(int i=0;i<4;i++){
    int e=i*128+t;
    int row=e>>4, c0=(e&15)*8;
    uint4 raw=*reinterpret_cast<const uint4*>(y2+(g*32+(size_t)row)*128+c0);
    unsigned u[4]={raw.x,raw.y,raw.z,raw.w};
    #pragma unroll
    for(int k=0;k<4;k++){
      int c=c0+2*k;
      float lo=__uint_as_float(u[k]<<16), hi=__uint_as_float(u[k]&0xFFFF0000u);
      float a=lo*ssl[c]+ssl[128+c]; float bq=hi*ssl[c+1]+ssl[128+c+1];
      h[grp][row*130+c]  = a>0.f?a:0.f;
      h[grp][row*130+c+1]= bq>0.f?bq:0.f;
    }
  }
  float cx=out0[g*3], cy=out0[g*3+1], cz=out0[g*3+2];
  uLds[grp][t]=cx*M[t]+cy*M[128+t]+cz*M[256+t];
  __syncthreads();
  {
    int row=t&31, q=t>>5;
    float sc=0.f;
    const float* hr=&h[grp][row*130];
    const float* ur=&uLds[grp][0];
    #pragma unroll
    for(int c=0;c<32;c++) sc += hr[q*32+c]*ur[q*32+c];
    partLds[grp][q][row]=sc;
  }
  __syncthreads();
  if(t<32){
    float s=(partLds[grp][0][t]+partLds[grp][1][t])+(partLds[grp][2][t]+partLds[grp][3][t]);
    s*=0.08838834764831845f; // 1/sqrt(128)
    float mx=s;
    #pragma unroll
    for(int m=16;m>=1;m>>=1) mx=fmaxf(mx,__shfl_xor(mx,m));
    float p=expf(s-mx);
    float sum=p;
    #pragma unroll
    for(int m=16;m>=1;m>>=1) sum+=__shfl_xor(sum,m);
    sLds[grp][t]=p/sum;
  }
  __syncthreads();
  float hb=0.f;
  for(int k=0;k<32;k++) hb+=sLds[grp][k]*h[grp][k*130+t];
  hbL[grp][t]=hb;
  __syncthreads();
  float acc=0.f;
  #pragma unroll 4
  for(int c=0;c<128;c++) acc += hbL[grp][c]*Wv[c*128+t];
  out1[g*128+t]=acc;
}

extern "C" void kernel_launch(void* const* d_in, const int* in_sizes, int n_in,
                              void* d_out, int out_size, void* d_ws, size_t ws_size,
                              hipStream_t stream){
  (void)in_sizes; (void)n_in; (void)out_size; (void)ws_size;
  const float* xyz=(const float*)d_in[0];
  const float* pts=(const float*)d_in[1];
  const float* W0=(const float*)d_in[2];  const float* b0=(const float*)d_in[3];
  const float* g0=(const float*)d_in[4];  const float* be0=(const float*)d_in[5];
  const float* W1=(const float*)d_in[6];  const float* b1=(const float*)d_in[7];
  const float* g1=(const float*)d_in[8];  const float* be1=(const float*)d_in[9];
  const float* W2=(const float*)d_in[10]; const float* b2=(const float*)d_in[11];
  const float* g2=(const float*)d_in[12]; const float* be2=(const float*)d_in[13];
  const float* Wq=(const float*)d_in[14]; const float* Wk=(const float*)d_in[15];
  const float* Wv=(const float*)d_in[16];
  float* out0=(float*)d_out;
  float* out1=out0 + (size_t)8*1024*3;
  float* out2=out1 + (size_t)8192*128;

  char* ws=(char*)d_ws; size_t off=0;
  int* idxw=(int*)(ws+off);                    off += (size_t)8192*32*4;
  __hip_bfloat16* fa=(__hip_bfloat16*)(ws+off); off += (size_t)262144*64*2;
  __hip_bfloat16* fb=(__hip_bfloat16*)(ws+off); off += (size_t)262144*64*2;
  __hip_bfloat16* fc=(__hip_bfloat16*)(ws+off); off += (size_t)262144*128*2;
  float* P =(float*)(ws+off);                  off += (size_t)256*4096*4;
  float* ss0=(float*)(ws+off);                 off += 256*4;
  float* ss1=(float*)(ws+off);                 off += 256*4;
  float* ss2=(float*)(ws+off);                 off += 256*4;
  float* M =(float*)(ws+off);                  off += 3*128*4 + 128;
  unsigned short* Wt0=(unsigned short*)(ws+off); off += (size_t)64*72*2;
  unsigned short* Wt1=(unsigned short*)(ws+off); off += (size_t)64*72*2;
  unsigned short* Wt2=(unsigned short*)(ws+off); off += (size_t)128*72*2;

  hipLaunchKernelGGL(prep_kernel,  dim3(1),    dim3(256),  0, stream, W0, W1, W2, Wq, Wk, Wt0, Wt1, Wt2, M);
  hipLaunchKernelGGL(fps_kernel,   dim3(8),    dim3(256),  0, stream, xyz, out0);
  hipLaunchKernelGGL(ballq_kernel, dim3(1024), dim3(512),  0, stream, xyz, out0, idxw, out2);
  hipLaunchKernelGGL(l0_mfma,      dim3(4096), dim3(256),  0, stream, xyz, pts, out0, idxw, W0, b0, Wt0, fa, P);
  hipLaunchKernelGGL(fin_kernel,   dim3(64),   dim3(64),   0, stream, P, g0, be0, ss0);
  hipLaunchKernelGGL((lmid_mfma<64,64>),  dim3(4096), dim3(256), 0, stream, fa, ss0, Wt1, b1, fb, P);
  hipLaunchKernelGGL(fin_kernel,   dim3(64),   dim3(64),   0, stream, P, g1, be1, ss1);
  hipLaunchKernelGGL((lmid_mfma<64,128>), dim3(4096), dim3(256), 0, stream, fb, ss1, Wt2, b2, fc, P);
  hipLaunchKernelGGL(fin_kernel,   dim3(128),  dim3(64),   0, stream, P, g2, be2, ss2);
  hipLaunchKernelGGL(sh_kernel,    dim3(4096), dim3(256),  0, stream, fc, ss2, M, out0, Wv, out1);
}